// Round 6
// baseline (291.566 us; speedup 1.0000x reference)
//
#include <hip/hip_runtime.h>
#include <math.h>

#define NN 50000          // nodes
#define NE 800000         // edges (without self loops)
#define NT (NE + NN)      // edges incl self loops
#define SCAN_BLK 1024
#define NSCAN ((NN + SCAN_BLK - 1) / SCAN_BLK)   // 49

// pack two fp32 -> bf16x2 (RNE); unpack is just shifts
__device__ __forceinline__ unsigned pk_bf16x2(float x, float y) {
  unsigned ux = __float_as_uint(x); ux = ux + 0x7FFFu + ((ux >> 16) & 1u);
  unsigned uy = __float_as_uint(y); uy = uy + 0x7FFFu + ((uy >> 16) & 1u);
  return (ux >> 16) | (uy & 0xFFFF0000u);
}

// ================= CSR build =================
__global__ __launch_bounds__(256) void k_csr_zero(int* deg) {
  int i = blockIdx.x * 256 + threadIdx.x;
  if (i < NN) deg[i] = 0;
}

__global__ __launch_bounds__(256) void k_csr_count(const int* __restrict__ dst, int* __restrict__ deg) {
  int i = blockIdx.x * 256 + threadIdx.x;
  if (i >= NT) return;
  int d = (i < NE) ? dst[i] : (i - NE);
  atomicAdd(&deg[d], 1);
}

__global__ __launch_bounds__(SCAN_BLK) void k_scan1(const int* __restrict__ deg,
                                                    int* __restrict__ rowptr, int* __restrict__ part) {
  __shared__ int s[SCAN_BLK];
  int t = threadIdx.x;
  int g = blockIdx.x * SCAN_BLK + t;
  s[t] = (g < NN) ? deg[g] : 0;
  __syncthreads();
  for (int off = 1; off < SCAN_BLK; off <<= 1) {
    int u = (t >= off) ? s[t - off] : 0;
    __syncthreads();
    s[t] += u;
    __syncthreads();
  }
  if (g < NN) rowptr[g + 1] = s[t];
  if (t == SCAN_BLK - 1) part[blockIdx.x] = s[t];
}

// single-wave shfl scan over the 49 partials
__global__ void k_scan2(int* part) {
  int l = threadIdx.x & 63;
  int v = (l < NSCAN) ? part[l] : 0;
#pragma unroll
  for (int off = 1; off < 64; off <<= 1) {
    int u = __shfl_up(v, off);
    if (l >= off) v += u;
  }
  int ex = __shfl_up(v, 1);
  if (l == 0) ex = 0;
  if (l < NSCAN) part[l] = ex;
}

// finalize rowptr AND pre-init cursor[n] = rowptr[n] (scatter then needs no rowptr read)
__global__ __launch_bounds__(SCAN_BLK) void k_scan3(int* __restrict__ rowptr, int* __restrict__ cursor,
                                                    const int* __restrict__ part) {
  int t = threadIdx.x;
  int g = blockIdx.x * SCAN_BLK + t;
  if (g < NN) {
    int v = rowptr[g + 1] + part[blockIdx.x];
    rowptr[g + 1] = v;
    if (g + 1 < NN) cursor[g + 1] = v;
  }
  if (g == 0) { rowptr[0] = 0; cursor[0] = 0; }
}

__global__ __launch_bounds__(256) void k_csr_scatter(const int* __restrict__ src, const int* __restrict__ dst,
                                                     int* __restrict__ cursor, int* __restrict__ csr_src) {
  int i = blockIdx.x * 256 + threadIdx.x;
  if (i >= NT) return;
  int s, d;
  if (i < NE) { s = src[i]; d = dst[i]; } else { s = d = i - NE; }
  int pos = atomicAdd(&cursor[d], 1);
  csr_src[pos] = s;
}

// ================= layer 1 GEMM: x[50000x128] @ W1[128x128] -> bf16 h1u =================
__global__ __launch_bounds__(128, 2) void k_gemm1(
    const float* __restrict__ x, const float* __restrict__ W1,
    const float* __restrict__ asw_g, const float* __restrict__ adw_g,
    unsigned* __restrict__ h1u, float* __restrict__ as1, float* __restrict__ ad1) {
  __shared__ float sA[32][64];     // [k][row]
  __shared__ float sB[32][128];    // [k][col]
  const int t = threadIdx.x;
  const int tc = t & 15;           // 16 col groups x 8 cols
  const int tr = t >> 4;           // 8 row groups x 8 rows
  const int n0 = blockIdx.x * 64;

  float asw_t[8], adw_t[8];
#pragma unroll
  for (int j = 0; j < 8; ++j) { asw_t[j] = asw_g[tc * 8 + j]; adw_t[j] = adw_g[tc * 8 + j]; }

  float acc[8][8];
#pragma unroll
  for (int i = 0; i < 8; ++i)
#pragma unroll
    for (int j = 0; j < 8; ++j) acc[i][j] = 0.f;

  for (int kc = 0; kc < 128; kc += 32) {
#pragma unroll
    for (int f = 0; f < 4; ++f) {
      int id = t * 4 + f;
      int row = id >> 3;
      int q = id & 7;
      float4 v = make_float4(0.f, 0.f, 0.f, 0.f);
      int n = n0 + row;
      if (n < NN) v = *(const float4*)&x[(long long)n * 128 + kc + q * 4];
      sA[q * 4 + 0][row] = v.x; sA[q * 4 + 1][row] = v.y;
      sA[q * 4 + 2][row] = v.z; sA[q * 4 + 3][row] = v.w;
    }
#pragma unroll
    for (int f = 0; f < 8; ++f) {
      int id = t * 8 + f;
      int kk = id >> 5;
      int c4 = id & 31;
      *(float4*)&sB[kk][c4 * 4] = *(const float4*)&W1[(long long)(kc + kk) * 128 + c4 * 4];
    }
    __syncthreads();
#pragma unroll 4
    for (int kk = 0; kk < 32; ++kk) {
      float a[8], b[8];
      *(float4*)&a[0] = *(const float4*)&sA[kk][tr * 8];
      *(float4*)&a[4] = *(const float4*)&sA[kk][tr * 8 + 4];
      *(float4*)&b[0] = *(const float4*)&sB[kk][tc * 8];
      *(float4*)&b[4] = *(const float4*)&sB[kk][tc * 8 + 4];
#pragma unroll
      for (int i = 0; i < 8; ++i)
#pragma unroll
        for (int j = 0; j < 8; ++j) acc[i][j] += a[i] * b[j];
    }
    __syncthreads();
  }

  const int head = tc >> 3;
#pragma unroll
  for (int i = 0; i < 8; ++i) {
    int n = n0 + tr * 8 + i;
    if (n >= NN) break;
    uint4 pv;
    pv.x = pk_bf16x2(acc[i][0], acc[i][1]);
    pv.y = pk_bf16x2(acc[i][2], acc[i][3]);
    pv.z = pk_bf16x2(acc[i][4], acc[i][5]);
    pv.w = pk_bf16x2(acc[i][6], acc[i][7]);
    *(uint4*)&h1u[(long long)n * 64 + tc * 4] = pv;
    float vs = 0.f, vd = 0.f;
#pragma unroll
    for (int j = 0; j < 8; ++j) { vs += acc[i][j] * asw_t[j]; vd += acc[i][j] * adw_t[j]; }
    vs += __shfl_xor(vs, 1); vd += __shfl_xor(vd, 1);
    vs += __shfl_xor(vs, 2); vd += __shfl_xor(vd, 2);
    vs += __shfl_xor(vs, 4); vd += __shfl_xor(vd, 4);
    if ((tc & 7) == 0) { as1[n * 2 + head] = vs; ad1[n * 2 + head] = vd; }
  }
}

// ================= layer 1 fused GAT: stats + broadcast-weighted SpMM + mean + ELU =================
// wave per node (4/block); lane p owns packed channels (2p,2p+1); head h=p>>5
__global__ __launch_bounds__(256) void k_gat1(
    const int* __restrict__ rowptr, const int* __restrict__ csr_src,
    const unsigned* __restrict__ h1u, const float2* __restrict__ as1,
    const float2* __restrict__ ad1, const float* __restrict__ b1,
    float* __restrict__ out1) {
  const int t = threadIdx.x;
  const int n = blockIdx.x * 4 + (t >> 6);
  if (n >= NN) return;
  const int p = t & 63;
  const int h = p >> 5;
  const int beg = rowptr[n], end = rowptr[n + 1];
  const float2 adn = ad1[n];

  // pass 1: per-lane online (m,d) for both heads over 64-stride slice, then wave merge
  float m0 = -1e30f, d0 = 0.f, m1 = -1e30f, d1 = 0.f;
  for (int k = beg + p; k < end; k += 64) {
    float2 a = as1[csr_src[k]];
    float e0 = a.x + adn.x; e0 = fmaxf(e0, 0.2f * e0);
    float e1 = a.y + adn.y; e1 = fmaxf(e1, 0.2f * e1);
    if (e0 > m0) { d0 *= __expf(m0 - e0); m0 = e0; }
    d0 += __expf(e0 - m0);
    if (e1 > m1) { d1 *= __expf(m1 - e1); m1 = e1; }
    d1 += __expf(e1 - m1);
  }
#pragma unroll
  for (int off = 1; off < 64; off <<= 1) {
    float mo = __shfl_xor(m0, off), dd = __shfl_xor(d0, off);
    float mn = fmaxf(m0, mo);
    d0 = d0 * __expf(m0 - mn) + dd * __expf(mo - mn);
    m0 = mn;
    mo = __shfl_xor(m1, off); dd = __shfl_xor(d1, off);
    mn = fmaxf(m1, mo);
    d1 = d1 * __expf(m1 - mn) + dd * __expf(mo - mn);
    m1 = mn;
  }
  const float inv = 1.f / ((h ? d1 : d0) + 1e-16f);

  // pass 2: 64-edge chunks; lane computes w for ITS edge once, then wave
  // broadcasts (s,w) per edge via readlane-shuffles (uniform index)
  float acc0 = 0.f, acc1 = 0.f;
  for (int c0 = beg; c0 < end; c0 += 64) {
    int nc = end - c0; if (nc > 64) nc = 64;
    int s_my = 0; float w0_my = 0.f, w1_my = 0.f;
    if (p < nc) {
      s_my = csr_src[c0 + p];
      float2 a = as1[s_my];
      float e0 = a.x + adn.x; e0 = fmaxf(e0, 0.2f * e0);
      float e1 = a.y + adn.y; e1 = fmaxf(e1, 0.2f * e1);
      w0_my = __expf(e0 - m0);
      w1_my = __expf(e1 - m1);
    }
#pragma unroll 4
    for (int j = 0; j < nc; ++j) {
      int s = __shfl(s_my, j);
      float w0b = __shfl(w0_my, j);
      float w1b = __shfl(w1_my, j);
      float w = h ? w1b : w0b;
      unsigned v = h1u[(s << 6) + p];
      acc0 += w * __uint_as_float(v << 16);
      acc1 += w * __uint_as_float(v & 0xFFFF0000u);
    }
  }
  acc0 *= inv; acc1 *= inv;
  acc0 += __shfl_xor(acc0, 32);
  acc1 += __shfl_xor(acc1, 32);
  if (p < 32) {
    float u0 = 0.5f * acc0 + b1[2 * p];
    float u1 = 0.5f * acc1 + b1[2 * p + 1];
    u0 = u0 > 0.f ? u0 : expm1f(u0);
    u1 = u1 > 0.f ? u1 : expm1f(u1);
    *(float2*)&out1[(long long)n * 64 + 2 * p] = make_float2(u0, u1);
  }
}

// ================= layer 2 GEMM: out1[50000x64] @ W2[64x64] -> bf16 h2u =================
__global__ __launch_bounds__(128, 2) void k_gemm2(
    const float* __restrict__ in, const float* __restrict__ W2,
    const float* __restrict__ asw_g, const float* __restrict__ adw_g,
    unsigned* __restrict__ h2u, float* __restrict__ as2, float* __restrict__ ad2) {
  __shared__ float sB[64][64];
  __shared__ float sA[32][132];
  const int t = threadIdx.x;
  const int tc = t & 7;
  const int tr = t >> 3;
  const int n0 = blockIdx.x * 128;

#pragma unroll
  for (int f = 0; f < 8; ++f) {
    int id = t * 8 + f;
    int kk = id >> 4;
    int c4 = id & 15;
    *(float4*)&sB[kk][c4 * 4] = *(const float4*)&W2[kk * 64 + c4 * 4];
  }

  float asw_t[8], adw_t[8];
#pragma unroll
  for (int j = 0; j < 8; ++j) { asw_t[j] = asw_g[tc * 8 + j]; adw_t[j] = adw_g[tc * 8 + j]; }

  float acc[8][8];
#pragma unroll
  for (int i = 0; i < 8; ++i)
#pragma unroll
    for (int j = 0; j < 8; ++j) acc[i][j] = 0.f;

  for (int kc = 0; kc < 64; kc += 32) {
#pragma unroll
    for (int f = 0; f < 8; ++f) {
      int id = f * 128 + t;
      int row = id >> 3;
      int q = id & 7;
      float4 v = make_float4(0.f, 0.f, 0.f, 0.f);
      int n = n0 + row;
      if (n < NN) v = *(const float4*)&in[(long long)n * 64 + kc + q * 4];
      sA[q * 4 + 0][row] = v.x; sA[q * 4 + 1][row] = v.y;
      sA[q * 4 + 2][row] = v.z; sA[q * 4 + 3][row] = v.w;
    }
    __syncthreads();
#pragma unroll 4
    for (int kk = 0; kk < 32; ++kk) {
      float a[8], b[8];
      *(float4*)&a[0] = *(const float4*)&sA[kk][tr * 8];
      *(float4*)&a[4] = *(const float4*)&sA[kk][tr * 8 + 4];
      *(float4*)&b[0] = *(const float4*)&sB[kc + kk][tc * 8];
      *(float4*)&b[4] = *(const float4*)&sB[kc + kk][tc * 8 + 4];
#pragma unroll
      for (int i = 0; i < 8; ++i)
#pragma unroll
        for (int j = 0; j < 8; ++j) acc[i][j] += a[i] * b[j];
    }
    __syncthreads();
  }

#pragma unroll
  for (int i = 0; i < 8; ++i) {
    int n = n0 + tr * 8 + i;
    if (n >= NN) break;
    uint4 pv;
    pv.x = pk_bf16x2(acc[i][0], acc[i][1]);
    pv.y = pk_bf16x2(acc[i][2], acc[i][3]);
    pv.z = pk_bf16x2(acc[i][4], acc[i][5]);
    pv.w = pk_bf16x2(acc[i][6], acc[i][7]);
    *(uint4*)&h2u[(long long)n * 32 + tc * 4] = pv;
    float vs = 0.f, vd = 0.f;
#pragma unroll
    for (int j = 0; j < 8; ++j) { vs += acc[i][j] * asw_t[j]; vd += acc[i][j] * adw_t[j]; }
    vs += __shfl_xor(vs, 1); vd += __shfl_xor(vd, 1);
    vs += __shfl_xor(vs, 2); vd += __shfl_xor(vd, 2);
    vs += __shfl_xor(vs, 4); vd += __shfl_xor(vd, 4);
    if (tc == 0) { as2[n] = vs; ad2[n] = vd; }
  }
}

// ================= layer 2 fused GAT + classifier + log_softmax =================
// wave per node; half-waves take alternate edges; lane q owns packed channels (2q,2q+1)
__global__ __launch_bounds__(256) void k_gat2(
    const int* __restrict__ rowptr, const int* __restrict__ csr_src,
    const unsigned* __restrict__ h2u, const float* __restrict__ as2,
    const float* __restrict__ ad2, const float* __restrict__ b2,
    const float* __restrict__ Wc, const float* __restrict__ bc,
    float* __restrict__ out) {
  const int t = threadIdx.x;
  const int n = blockIdx.x * 4 + (t >> 6);
  if (n >= NN) return;
  const int p = t & 63;
  const int half = p >> 5;
  const int q = p & 31;
  const int beg = rowptr[n], end = rowptr[n + 1];
  const float adn = ad2[n];

  // pass 1: stats
  float m = -1e30f, d = 0.f;
  for (int k = beg + p; k < end; k += 64) {
    float e = as2[csr_src[k]] + adn;
    e = fmaxf(e, 0.2f * e);
    if (e > m) { d *= __expf(m - e); m = e; }
    d += __expf(e - m);
  }
#pragma unroll
  for (int off = 1; off < 64; off <<= 1) {
    float mo = __shfl_xor(m, off), dd = __shfl_xor(d, off);
    float mn = fmaxf(m, mo);
    d = d * __expf(m - mn) + dd * __expf(mo - mn);
    m = mn;
  }
  const float inv = 1.f / (d + 1e-16f);

  // pass 2: 64-edge chunks; half-waves take alternate edges; clamped bpermute
  // index keeps all lanes active (never read an exited source lane)
  float acc0 = 0.f, acc1 = 0.f;
  for (int c0 = beg; c0 < end; c0 += 64) {
    int nc = end - c0; if (nc > 64) nc = 64;
    int s_my = 0; float w_my = 0.f;
    if (p < nc) {
      s_my = csr_src[c0 + p];
      float e = as2[s_my] + adn;
      e = fmaxf(e, 0.2f * e);
      w_my = __expf(e - m);
    }
    int niter = (nc + 1) >> 1;
#pragma unroll 4
    for (int i = 0; i < niter; ++i) {
      int j = 2 * i + half;
      int jj = j < nc ? j : 0;
      int s = __shfl(s_my, jj);
      float w = __shfl(w_my, jj);
      w = j < nc ? w : 0.f;
      unsigned v = h2u[(s << 5) + q];
      acc0 += w * __uint_as_float(v << 16);
      acc1 += w * __uint_as_float(v & 0xFFFF0000u);
    }
  }
  acc0 += __shfl_xor(acc0, 32);
  acc1 += __shfl_xor(acc1, 32);
  float v0 = acc0 * inv + b2[2 * q];
  float v1 = acc1 * inv + b2[2 * q + 1];
  v0 = v0 > 0.f ? v0 : expm1f(v0);
  v1 = v1 > 0.f ? v1 : expm1f(v1);
  float l0 = v0 * Wc[4 * q] + v1 * Wc[4 * q + 2];
  float l1 = v0 * Wc[4 * q + 1] + v1 * Wc[4 * q + 3];
#pragma unroll
  for (int off = 1; off < 32; off <<= 1) {
    l0 += __shfl_xor(l0, off);
    l1 += __shfl_xor(l1, off);
  }
  if (p == 0) {
    l0 += bc[0]; l1 += bc[1];
    float mx = fmaxf(l0, l1);
    float lse = mx + logf(expf(l0 - mx) + expf(l1 - mx));
    out[n * 2] = l0 - lse;
    out[n * 2 + 1] = l1 - lse;
  }
}

extern "C" void kernel_launch(void* const* d_in, const int* in_sizes, int n_in,
                              void* d_out, int out_size, void* d_ws, size_t ws_size,
                              hipStream_t stream) {
  const float* x    = (const float*)d_in[0];
  const int*   ei   = (const int*)d_in[1];
  const float* W1   = (const float*)d_in[2];
  const float* as1w = (const float*)d_in[3];
  const float* ad1w = (const float*)d_in[4];
  const float* b1   = (const float*)d_in[5];
  const float* W2   = (const float*)d_in[6];
  const float* as2w = (const float*)d_in[7];
  const float* ad2w = (const float*)d_in[8];
  const float* b2   = (const float*)d_in[9];
  const float* Wc   = (const float*)d_in[10];
  const float* bc   = (const float*)d_in[11];
  float* out = (float*)d_out;

  const int* src = ei;
  const int* dst = ei + NE;

  // ---- workspace layout ----
  char* p = (char*)d_ws;
  unsigned* h1u = (unsigned*)p; p += sizeof(unsigned) * (long long)NN * 64;  // bf16x2 h1
  unsigned* h2u = (unsigned*)p; p += sizeof(unsigned) * (long long)NN * 32;  // bf16x2 h2
  float* out1 = (float*)p; p += sizeof(float) * (long long)NN * 64;
  float* as1  = (float*)p; p += sizeof(float) * NN * 2;
  float* ad1  = (float*)p; p += sizeof(float) * NN * 2;
  float* as2  = (float*)p; p += sizeof(float) * NN;
  float* ad2  = (float*)p; p += sizeof(float) * NN;
  int* deg     = (int*)p; p += sizeof(int) * NN;
  int* cursor  = (int*)p; p += sizeof(int) * NN;
  int* rowptr  = (int*)p; p += sizeof(int) * (NN + 1);
  int* part    = (int*)p; p += sizeof(int) * ((NSCAN + 63) & ~63);
  int* csr_src = (int*)p; p += sizeof(int) * (long long)NT;

  // ---- CSR build (graph shared by both layers) ----
  k_csr_zero<<<(NN + 255) / 256, 256, 0, stream>>>(deg);
  k_csr_count<<<(NT + 255) / 256, 256, 0, stream>>>(dst, deg);
  k_scan1<<<NSCAN, SCAN_BLK, 0, stream>>>(deg, rowptr, part);
  k_scan2<<<1, 64, 0, stream>>>(part);
  k_scan3<<<NSCAN, SCAN_BLK, 0, stream>>>(rowptr, cursor, part);
  k_csr_scatter<<<(NT + 255) / 256, 256, 0, stream>>>(src, dst, cursor, csr_src);

  // ---- layer 1 ----
  k_gemm1<<<(NN + 63) / 64, 128, 0, stream>>>(x, W1, as1w, ad1w, h1u, as1, ad1);
  k_gat1<<<(NN + 3) / 4, 256, 0, stream>>>(rowptr, csr_src, h1u, (const float2*)as1,
                                           (const float2*)ad1, b1, out1);

  // ---- layer 2 ----
  k_gemm2<<<(NN + 127) / 128, 128, 0, stream>>>(out1, W2, as2w, ad2w, h2u, as2, ad2);
  k_gat2<<<(NN + 3) / 4, 256, 0, stream>>>(rowptr, csr_src, h2u, as2, ad2, b2, Wc, bc, out);
}

// Round 7
// 233.630 us; speedup vs baseline: 1.2480x; 1.2480x over previous
//
#include <hip/hip_runtime.h>
#include <math.h>

#define NN 50000          // nodes
#define NE 800000         // edges (without self loops)
#define NT (NE + NN)      // edges incl self loops
#define SCAN_BLK 1024
#define NSCAN ((NN + SCAN_BLK - 1) / SCAN_BLK)   // 49

// pack two fp32 -> bf16x2 (RNE); unpack is just shifts
__device__ __forceinline__ unsigned pk_bf16x2(float x, float y) {
  unsigned ux = __float_as_uint(x); ux = ux + 0x7FFFu + ((ux >> 16) & 1u);
  unsigned uy = __float_as_uint(y); uy = uy + 0x7FFFu + ((uy >> 16) & 1u);
  return (ux >> 16) | (uy & 0xFFFF0000u);
}

// ================= CSR build =================
__global__ __launch_bounds__(256) void k_csr_zero(int* deg) {
  int i = blockIdx.x * 256 + threadIdx.x;
  if (i < NN) deg[i] = 0;
}

__global__ __launch_bounds__(256) void k_csr_count(const int* __restrict__ dst, int* __restrict__ deg) {
  int i = blockIdx.x * 256 + threadIdx.x;
  if (i >= NT) return;
  int d = (i < NE) ? dst[i] : (i - NE);
  atomicAdd(&deg[d], 1);
}

__global__ __launch_bounds__(SCAN_BLK) void k_scan1(const int* __restrict__ deg,
                                                    int* __restrict__ rowptr, int* __restrict__ part) {
  __shared__ int s[SCAN_BLK];
  int t = threadIdx.x;
  int g = blockIdx.x * SCAN_BLK + t;
  s[t] = (g < NN) ? deg[g] : 0;
  __syncthreads();
  for (int off = 1; off < SCAN_BLK; off <<= 1) {
    int u = (t >= off) ? s[t - off] : 0;
    __syncthreads();
    s[t] += u;
    __syncthreads();
  }
  if (g < NN) rowptr[g + 1] = s[t];
  if (t == SCAN_BLK - 1) part[blockIdx.x] = s[t];
}

// single-wave shfl scan over the 49 partials
__global__ void k_scan2(int* part) {
  int l = threadIdx.x & 63;
  int v = (l < NSCAN) ? part[l] : 0;
#pragma unroll
  for (int off = 1; off < 64; off <<= 1) {
    int u = __shfl_up(v, off);
    if (l >= off) v += u;
  }
  int ex = __shfl_up(v, 1);
  if (l == 0) ex = 0;
  if (l < NSCAN) part[l] = ex;
}

// finalize rowptr AND pre-init cursor[n] = rowptr[n]
__global__ __launch_bounds__(SCAN_BLK) void k_scan3(int* __restrict__ rowptr, int* __restrict__ cursor,
                                                    const int* __restrict__ part) {
  int t = threadIdx.x;
  int g = blockIdx.x * SCAN_BLK + t;
  if (g < NN) {
    int v = rowptr[g + 1] + part[blockIdx.x];
    rowptr[g + 1] = v;
    if (g + 1 < NN) cursor[g + 1] = v;
  }
  if (g == 0) { rowptr[0] = 0; cursor[0] = 0; }
}

__global__ __launch_bounds__(256) void k_csr_scatter(const int* __restrict__ src, const int* __restrict__ dst,
                                                     int* __restrict__ cursor, int* __restrict__ csr_src) {
  int i = blockIdx.x * 256 + threadIdx.x;
  if (i >= NT) return;
  int s, d;
  if (i < NE) { s = src[i]; d = dst[i]; } else { s = d = i - NE; }
  int pos = atomicAdd(&cursor[d], 1);
  csr_src[pos] = s;
}

// ================= layer 1 GEMM: x[50000x128] @ W1[128x128] -> bf16 h1u =================
__global__ __launch_bounds__(128, 2) void k_gemm1(
    const float* __restrict__ x, const float* __restrict__ W1,
    const float* __restrict__ asw_g, const float* __restrict__ adw_g,
    unsigned* __restrict__ h1u, float* __restrict__ as1, float* __restrict__ ad1) {
  __shared__ float sA[32][64];     // [k][row]
  __shared__ float sB[32][128];    // [k][col]
  const int t = threadIdx.x;
  const int tc = t & 15;           // 16 col groups x 8 cols
  const int tr = t >> 4;           // 8 row groups x 8 rows
  const int n0 = blockIdx.x * 64;

  float asw_t[8], adw_t[8];
#pragma unroll
  for (int j = 0; j < 8; ++j) { asw_t[j] = asw_g[tc * 8 + j]; adw_t[j] = adw_g[tc * 8 + j]; }

  float acc[8][8];
#pragma unroll
  for (int i = 0; i < 8; ++i)
#pragma unroll
    for (int j = 0; j < 8; ++j) acc[i][j] = 0.f;

  for (int kc = 0; kc < 128; kc += 32) {
#pragma unroll
    for (int f = 0; f < 4; ++f) {
      int id = t * 4 + f;
      int row = id >> 3;
      int q = id & 7;
      float4 v = make_float4(0.f, 0.f, 0.f, 0.f);
      int n = n0 + row;
      if (n < NN) v = *(const float4*)&x[(long long)n * 128 + kc + q * 4];
      sA[q * 4 + 0][row] = v.x; sA[q * 4 + 1][row] = v.y;
      sA[q * 4 + 2][row] = v.z; sA[q * 4 + 3][row] = v.w;
    }
#pragma unroll
    for (int f = 0; f < 8; ++f) {
      int id = t * 8 + f;
      int kk = id >> 5;
      int c4 = id & 31;
      *(float4*)&sB[kk][c4 * 4] = *(const float4*)&W1[(long long)(kc + kk) * 128 + c4 * 4];
    }
    __syncthreads();
#pragma unroll 4
    for (int kk = 0; kk < 32; ++kk) {
      float a[8], b[8];
      *(float4*)&a[0] = *(const float4*)&sA[kk][tr * 8];
      *(float4*)&a[4] = *(const float4*)&sA[kk][tr * 8 + 4];
      *(float4*)&b[0] = *(const float4*)&sB[kk][tc * 8];
      *(float4*)&b[4] = *(const float4*)&sB[kk][tc * 8 + 4];
#pragma unroll
      for (int i = 0; i < 8; ++i)
#pragma unroll
        for (int j = 0; j < 8; ++j) acc[i][j] += a[i] * b[j];
    }
    __syncthreads();
  }

  const int head = tc >> 3;
#pragma unroll
  for (int i = 0; i < 8; ++i) {
    int n = n0 + tr * 8 + i;
    if (n >= NN) break;
    uint4 pv;
    pv.x = pk_bf16x2(acc[i][0], acc[i][1]);
    pv.y = pk_bf16x2(acc[i][2], acc[i][3]);
    pv.z = pk_bf16x2(acc[i][4], acc[i][5]);
    pv.w = pk_bf16x2(acc[i][6], acc[i][7]);
    *(uint4*)&h1u[(long long)n * 64 + tc * 4] = pv;
    float vs = 0.f, vd = 0.f;
#pragma unroll
    for (int j = 0; j < 8; ++j) { vs += acc[i][j] * asw_t[j]; vd += acc[i][j] * adw_t[j]; }
    vs += __shfl_xor(vs, 1); vd += __shfl_xor(vd, 1);
    vs += __shfl_xor(vs, 2); vd += __shfl_xor(vd, 2);
    vs += __shfl_xor(vs, 4); vd += __shfl_xor(vd, 4);
    if ((tc & 7) == 0) { as1[n * 2 + head] = vs; ad1[n * 2 + head] = vd; }
  }
}

// ================= layer 1 fused GAT: LDS-broadcast weighted SpMM + mean + ELU =================
// wave per node (4/block); lane p owns packed channels (2p,2p+1); head h=p>>5
__global__ __launch_bounds__(256) void k_gat1(
    const int* __restrict__ rowptr, const int* __restrict__ csr_src,
    const unsigned* __restrict__ h1u, const float2* __restrict__ as1,
    const float2* __restrict__ ad1, const float* __restrict__ b1,
    float* __restrict__ out1) {
  __shared__ float2 sw[4][2][64];     // [wave][head][slot] = {s_bits, w}
  const int t = threadIdx.x;
  const int wv = t >> 6;
  const int n = blockIdx.x * 4 + wv;
  if (n >= NN) return;
  const int p = t & 63;
  const int h = p >> 5;
  const int beg = rowptr[n], end = rowptr[n + 1];
  const int deg = end - beg;
  const float2 adn = ad1[n];

  float acc0 = 0.f, acc1 = 0.f;
  float inv;

  if (deg <= 64) {
    // ---- fast path: single chunk; lane p handles edge p ----
    int s = 0; float e0 = -1e30f, e1 = -1e30f;
    if (p < deg) {
      s = csr_src[beg + p];
      float2 a = as1[s];
      e0 = a.x + adn.x; e0 = fmaxf(e0, 0.2f * e0);
      e1 = a.y + adn.y; e1 = fmaxf(e1, 0.2f * e1);
    }
    float m0 = e0, m1 = e1;
#pragma unroll
    for (int off = 1; off < 64; off <<= 1) {
      m0 = fmaxf(m0, __shfl_xor(m0, off));
      m1 = fmaxf(m1, __shfl_xor(m1, off));
    }
    float w0 = (p < deg) ? __expf(e0 - m0) : 0.f;
    float w1 = (p < deg) ? __expf(e1 - m1) : 0.f;
    float d0 = w0, d1 = w1;
#pragma unroll
    for (int off = 1; off < 64; off <<= 1) {
      d0 += __shfl_xor(d0, off);
      d1 += __shfl_xor(d1, off);
    }
    sw[wv][0][p] = make_float2(__int_as_float(s), w0);
    sw[wv][1][p] = make_float2(__int_as_float(s), w1);
    __builtin_amdgcn_wave_barrier();
    inv = 1.f / ((h ? d1 : d0) + 1e-16f);

    int j = 0;
    for (; j + 4 <= deg; j += 4) {
      float2 a0 = sw[wv][h][j], a1 = sw[wv][h][j + 1],
             a2 = sw[wv][h][j + 2], a3 = sw[wv][h][j + 3];
      unsigned v0 = h1u[(__float_as_int(a0.x) << 6) + p];
      unsigned v1 = h1u[(__float_as_int(a1.x) << 6) + p];
      unsigned v2 = h1u[(__float_as_int(a2.x) << 6) + p];
      unsigned v3 = h1u[(__float_as_int(a3.x) << 6) + p];
      acc0 += a0.y * __uint_as_float(v0 << 16); acc1 += a0.y * __uint_as_float(v0 & 0xFFFF0000u);
      acc0 += a1.y * __uint_as_float(v1 << 16); acc1 += a1.y * __uint_as_float(v1 & 0xFFFF0000u);
      acc0 += a2.y * __uint_as_float(v2 << 16); acc1 += a2.y * __uint_as_float(v2 & 0xFFFF0000u);
      acc0 += a3.y * __uint_as_float(v3 << 16); acc1 += a3.y * __uint_as_float(v3 & 0xFFFF0000u);
    }
    for (; j < deg; ++j) {
      float2 a = sw[wv][h][j];
      unsigned v = h1u[(__float_as_int(a.x) << 6) + p];
      acc0 += a.y * __uint_as_float(v << 16); acc1 += a.y * __uint_as_float(v & 0xFFFF0000u);
    }
  } else {
    // ---- slow path (deg > 64): strided online stats, then chunked LDS agg ----
    float m0 = -1e30f, d0 = 0.f, m1 = -1e30f, d1 = 0.f;
    for (int k = beg + p; k < end; k += 64) {
      float2 a = as1[csr_src[k]];
      float e0 = a.x + adn.x; e0 = fmaxf(e0, 0.2f * e0);
      float e1 = a.y + adn.y; e1 = fmaxf(e1, 0.2f * e1);
      if (e0 > m0) { d0 *= __expf(m0 - e0); m0 = e0; }
      d0 += __expf(e0 - m0);
      if (e1 > m1) { d1 *= __expf(m1 - e1); m1 = e1; }
      d1 += __expf(e1 - m1);
    }
#pragma unroll
    for (int off = 1; off < 64; off <<= 1) {
      float mo = __shfl_xor(m0, off), dd = __shfl_xor(d0, off);
      float mn = fmaxf(m0, mo);
      d0 = d0 * __expf(m0 - mn) + dd * __expf(mo - mn);
      m0 = mn;
      mo = __shfl_xor(m1, off); dd = __shfl_xor(d1, off);
      mn = fmaxf(m1, mo);
      d1 = d1 * __expf(m1 - mn) + dd * __expf(mo - mn);
      m1 = mn;
    }
    inv = 1.f / ((h ? d1 : d0) + 1e-16f);
    for (int c0 = beg; c0 < end; c0 += 64) {
      int nc = end - c0; if (nc > 64) nc = 64;
      int s = 0; float w0 = 0.f, w1 = 0.f;
      if (p < nc) {
        s = csr_src[c0 + p];
        float2 a = as1[s];
        float e0 = a.x + adn.x; e0 = fmaxf(e0, 0.2f * e0);
        float e1 = a.y + adn.y; e1 = fmaxf(e1, 0.2f * e1);
        w0 = __expf(e0 - m0);
        w1 = __expf(e1 - m1);
      }
      __builtin_amdgcn_wave_barrier();
      sw[wv][0][p] = make_float2(__int_as_float(s), w0);
      sw[wv][1][p] = make_float2(__int_as_float(s), w1);
      __builtin_amdgcn_wave_barrier();
      for (int j = 0; j < nc; ++j) {
        float2 a = sw[wv][h][j];
        unsigned v = h1u[(__float_as_int(a.x) << 6) + p];
        acc0 += a.y * __uint_as_float(v << 16); acc1 += a.y * __uint_as_float(v & 0xFFFF0000u);
      }
      __builtin_amdgcn_wave_barrier();
    }
  }

  acc0 *= inv; acc1 *= inv;
  acc0 += __shfl_xor(acc0, 32);
  acc1 += __shfl_xor(acc1, 32);
  if (p < 32) {
    float u0 = 0.5f * acc0 + b1[2 * p];
    float u1 = 0.5f * acc1 + b1[2 * p + 1];
    u0 = u0 > 0.f ? u0 : expm1f(u0);
    u1 = u1 > 0.f ? u1 : expm1f(u1);
    *(float2*)&out1[(long long)n * 64 + 2 * p] = make_float2(u0, u1);
  }
}

// ================= layer 2 GEMM: out1[50000x64] @ W2[64x64] -> bf16 h2u =================
__global__ __launch_bounds__(128, 2) void k_gemm2(
    const float* __restrict__ in, const float* __restrict__ W2,
    const float* __restrict__ asw_g, const float* __restrict__ adw_g,
    unsigned* __restrict__ h2u, float* __restrict__ as2, float* __restrict__ ad2) {
  __shared__ float sB[64][64];
  __shared__ float sA[32][132];
  const int t = threadIdx.x;
  const int tc = t & 7;
  const int tr = t >> 3;
  const int n0 = blockIdx.x * 128;

#pragma unroll
  for (int f = 0; f < 8; ++f) {
    int id = t * 8 + f;
    int kk = id >> 4;
    int c4 = id & 15;
    *(float4*)&sB[kk][c4 * 4] = *(const float4*)&W2[kk * 64 + c4 * 4];
  }

  float asw_t[8], adw_t[8];
#pragma unroll
  for (int j = 0; j < 8; ++j) { asw_t[j] = asw_g[tc * 8 + j]; adw_t[j] = adw_g[tc * 8 + j]; }

  float acc[8][8];
#pragma unroll
  for (int i = 0; i < 8; ++i)
#pragma unroll
    for (int j = 0; j < 8; ++j) acc[i][j] = 0.f;

  for (int kc = 0; kc < 64; kc += 32) {
#pragma unroll
    for (int f = 0; f < 8; ++f) {
      int id = f * 128 + t;
      int row = id >> 3;
      int q = id & 7;
      float4 v = make_float4(0.f, 0.f, 0.f, 0.f);
      int n = n0 + row;
      if (n < NN) v = *(const float4*)&in[(long long)n * 64 + kc + q * 4];
      sA[q * 4 + 0][row] = v.x; sA[q * 4 + 1][row] = v.y;
      sA[q * 4 + 2][row] = v.z; sA[q * 4 + 3][row] = v.w;
    }
    __syncthreads();
#pragma unroll 4
    for (int kk = 0; kk < 32; ++kk) {
      float a[8], b[8];
      *(float4*)&a[0] = *(const float4*)&sA[kk][tr * 8];
      *(float4*)&a[4] = *(const float4*)&sA[kk][tr * 8 + 4];
      *(float4*)&b[0] = *(const float4*)&sB[kc + kk][tc * 8];
      *(float4*)&b[4] = *(const float4*)&sB[kc + kk][tc * 8 + 4];
#pragma unroll
      for (int i = 0; i < 8; ++i)
#pragma unroll
        for (int j = 0; j < 8; ++j) acc[i][j] += a[i] * b[j];
    }
    __syncthreads();
  }

#pragma unroll
  for (int i = 0; i < 8; ++i) {
    int n = n0 + tr * 8 + i;
    if (n >= NN) break;
    uint4 pv;
    pv.x = pk_bf16x2(acc[i][0], acc[i][1]);
    pv.y = pk_bf16x2(acc[i][2], acc[i][3]);
    pv.z = pk_bf16x2(acc[i][4], acc[i][5]);
    pv.w = pk_bf16x2(acc[i][6], acc[i][7]);
    *(uint4*)&h2u[(long long)n * 32 + tc * 4] = pv;
    float vs = 0.f, vd = 0.f;
#pragma unroll
    for (int j = 0; j < 8; ++j) { vs += acc[i][j] * asw_t[j]; vd += acc[i][j] * adw_t[j]; }
    vs += __shfl_xor(vs, 1); vd += __shfl_xor(vd, 1);
    vs += __shfl_xor(vs, 2); vd += __shfl_xor(vd, 2);
    vs += __shfl_xor(vs, 4); vd += __shfl_xor(vd, 4);
    if (tc == 0) { as2[n] = vs; ad2[n] = vd; }
  }
}

// ================= layer 2 fused GAT + classifier + log_softmax =================
// wave per node; half-waves take alternate edges; lane q owns packed channels (2q,2q+1)
__global__ __launch_bounds__(256) void k_gat2(
    const int* __restrict__ rowptr, const int* __restrict__ csr_src,
    const unsigned* __restrict__ h2u, const float* __restrict__ as2,
    const float* __restrict__ ad2, const float* __restrict__ b2,
    const float* __restrict__ Wc, const float* __restrict__ bc,
    float* __restrict__ out) {
  __shared__ float2 sw[4][64];        // [wave][slot] = {s_bits, w}
  const int t = threadIdx.x;
  const int wv = t >> 6;
  const int n = blockIdx.x * 4 + wv;
  if (n >= NN) return;
  const int p = t & 63;
  const int half = p >> 5;
  const int q = p & 31;
  const int beg = rowptr[n], end = rowptr[n + 1];
  const int deg = end - beg;
  const float adn = ad2[n];

  float acc0 = 0.f, acc1 = 0.f;
  float inv;

  if (deg <= 64) {
    // ---- fast path ----
    int s = 0; float e = -1e30f;
    if (p < deg) {
      s = csr_src[beg + p];
      e = as2[s] + adn;
      e = fmaxf(e, 0.2f * e);
    }
    float m = e;
#pragma unroll
    for (int off = 1; off < 64; off <<= 1) m = fmaxf(m, __shfl_xor(m, off));
    float w = (p < deg) ? __expf(e - m) : 0.f;
    float d = w;
#pragma unroll
    for (int off = 1; off < 64; off <<= 1) d += __shfl_xor(d, off);
    sw[wv][p] = make_float2(__int_as_float(s), w);
    __builtin_amdgcn_wave_barrier();
    inv = 1.f / (d + 1e-16f);

    int niter = (deg + 1) >> 1;
    int i = 0;
    for (; i + 2 <= niter; i += 2) {
      float2 a0 = sw[wv][2 * i + half];
      float2 a1 = sw[wv][2 * i + 2 + half];
      unsigned v0 = h2u[(__float_as_int(a0.x) << 5) + q];
      unsigned v1 = h2u[(__float_as_int(a1.x) << 5) + q];
      acc0 += a0.y * __uint_as_float(v0 << 16); acc1 += a0.y * __uint_as_float(v0 & 0xFFFF0000u);
      acc0 += a1.y * __uint_as_float(v1 << 16); acc1 += a1.y * __uint_as_float(v1 & 0xFFFF0000u);
    }
    if (i < niter) {
      float2 a = sw[wv][2 * i + half];
      unsigned v = h2u[(__float_as_int(a.x) << 5) + q];
      acc0 += a.y * __uint_as_float(v << 16); acc1 += a.y * __uint_as_float(v & 0xFFFF0000u);
    }
  } else {
    // ---- slow path ----
    float m = -1e30f, d = 0.f;
    for (int k = beg + p; k < end; k += 64) {
      float e = as2[csr_src[k]] + adn;
      e = fmaxf(e, 0.2f * e);
      if (e > m) { d *= __expf(m - e); m = e; }
      d += __expf(e - m);
    }
#pragma unroll
    for (int off = 1; off < 64; off <<= 1) {
      float mo = __shfl_xor(m, off), dd = __shfl_xor(d, off);
      float mn = fmaxf(m, mo);
      d = d * __expf(m - mn) + dd * __expf(mo - mn);
      m = mn;
    }
    inv = 1.f / (d + 1e-16f);
    for (int c0 = beg; c0 < end; c0 += 64) {
      int nc = end - c0; if (nc > 64) nc = 64;
      int s = 0; float w = 0.f;
      if (p < nc) {
        s = csr_src[c0 + p];
        float e = as2[s] + adn;
        e = fmaxf(e, 0.2f * e);
        w = __expf(e - m);
      }
      __builtin_amdgcn_wave_barrier();
      sw[wv][p] = make_float2(__int_as_float(s), w);
      __builtin_amdgcn_wave_barrier();
      int niter = (nc + 1) >> 1;
      for (int i = 0; i < niter; ++i) {
        int j = 2 * i + half;
        float2 a = sw[wv][j < nc ? j : 0];
        float wj = (j < nc) ? a.y : 0.f;
        unsigned v = h2u[(__float_as_int(a.x) << 5) + q];
        acc0 += wj * __uint_as_float(v << 16); acc1 += wj * __uint_as_float(v & 0xFFFF0000u);
      }
      __builtin_amdgcn_wave_barrier();
    }
  }

  acc0 += __shfl_xor(acc0, 32);
  acc1 += __shfl_xor(acc1, 32);
  float v0 = acc0 * inv + b2[2 * q];
  float v1 = acc1 * inv + b2[2 * q + 1];
  v0 = v0 > 0.f ? v0 : expm1f(v0);
  v1 = v1 > 0.f ? v1 : expm1f(v1);
  float l0 = v0 * Wc[4 * q] + v1 * Wc[4 * q + 2];
  float l1 = v0 * Wc[4 * q + 1] + v1 * Wc[4 * q + 3];
#pragma unroll
  for (int off = 1; off < 32; off <<= 1) {
    l0 += __shfl_xor(l0, off);
    l1 += __shfl_xor(l1, off);
  }
  if (p == 0) {
    l0 += bc[0]; l1 += bc[1];
    float mx = fmaxf(l0, l1);
    float lse = mx + logf(expf(l0 - mx) + expf(l1 - mx));
    out[n * 2] = l0 - lse;
    out[n * 2 + 1] = l1 - lse;
  }
}

extern "C" void kernel_launch(void* const* d_in, const int* in_sizes, int n_in,
                              void* d_out, int out_size, void* d_ws, size_t ws_size,
                              hipStream_t stream) {
  const float* x    = (const float*)d_in[0];
  const int*   ei   = (const int*)d_in[1];
  const float* W1   = (const float*)d_in[2];
  const float* as1w = (const float*)d_in[3];
  const float* ad1w = (const float*)d_in[4];
  const float* b1   = (const float*)d_in[5];
  const float* W2   = (const float*)d_in[6];
  const float* as2w = (const float*)d_in[7];
  const float* ad2w = (const float*)d_in[8];
  const float* b2   = (const float*)d_in[9];
  const float* Wc   = (const float*)d_in[10];
  const float* bc   = (const float*)d_in[11];
  float* out = (float*)d_out;

  const int* src = ei;
  const int* dst = ei + NE;

  // ---- workspace layout ----
  char* p = (char*)d_ws;
  unsigned* h1u = (unsigned*)p; p += sizeof(unsigned) * (long long)NN * 64;  // bf16x2 h1
  unsigned* h2u = (unsigned*)p; p += sizeof(unsigned) * (long long)NN * 32;  // bf16x2 h2
  float* out1 = (float*)p; p += sizeof(float) * (long long)NN * 64;
  float* as1  = (float*)p; p += sizeof(float) * NN * 2;
  float* ad1  = (float*)p; p += sizeof(float) * NN * 2;
  float* as2  = (float*)p; p += sizeof(float) * NN;
  float* ad2  = (float*)p; p += sizeof(float) * NN;
  int* deg     = (int*)p; p += sizeof(int) * NN;
  int* cursor  = (int*)p; p += sizeof(int) * NN;
  int* rowptr  = (int*)p; p += sizeof(int) * (NN + 1);
  int* part    = (int*)p; p += sizeof(int) * ((NSCAN + 63) & ~63);
  int* csr_src = (int*)p; p += sizeof(int) * (long long)NT;

  // ---- CSR build (graph shared by both layers) ----
  k_csr_zero<<<(NN + 255) / 256, 256, 0, stream>>>(deg);
  k_csr_count<<<(NT + 255) / 256, 256, 0, stream>>>(dst, deg);
  k_scan1<<<NSCAN, SCAN_BLK, 0, stream>>>(deg, rowptr, part);
  k_scan2<<<1, 64, 0, stream>>>(part);
  k_scan3<<<NSCAN, SCAN_BLK, 0, stream>>>(rowptr, cursor, part);
  k_csr_scatter<<<(NT + 255) / 256, 256, 0, stream>>>(src, dst, cursor, csr_src);

  // ---- layer 1 ----
  k_gemm1<<<(NN + 63) / 64, 128, 0, stream>>>(x, W1, as1w, ad1w, h1u, as1, ad1);
  k_gat1<<<(NN + 3) / 4, 256, 0, stream>>>(rowptr, csr_src, h1u, (const float2*)as1,
                                           (const float2*)ad1, b1, out1);

  // ---- layer 2 ----
  k_gemm2<<<(NN + 127) / 128, 128, 0, stream>>>(out1, W2, as2w, ad2w, h2u, as2, ad2);
  k_gat2<<<(NN + 3) / 4, 256, 0, stream>>>(rowptr, csr_src, h2u, as2, ad2, b2, Wc, bc, out);
}

// Round 8
// 229.011 us; speedup vs baseline: 1.2732x; 1.0202x over previous
//
#include <hip/hip_runtime.h>
#include <math.h>

#define NN 50000          // nodes
#define NE 800000         // edges (without self loops)
#define NT (NE + NN)      // edges incl self loops
#define SCAN_BLK 1024
#define NSCAN ((NN + SCAN_BLK - 1) / SCAN_BLK)   // 49
#define NBUCK 196         // dst>>8 buckets (256 nodes each)
#define BE 8192           // edges per bucket-pass block
#define NBLK_B ((NT + BE - 1) / BE)              // 104

// pack two fp32 -> bf16x2 (RNE); unpack is just shifts
__device__ __forceinline__ unsigned pk_bf16x2(float x, float y) {
  unsigned ux = __float_as_uint(x); ux = ux + 0x7FFFu + ((ux >> 16) & 1u);
  unsigned uy = __float_as_uint(y); uy = uy + 0x7FFFu + ((uy >> 16) & 1u);
  return (ux >> 16) | (uy & 0xFFFF0000u);
}

// ================= CSR build =================
// deg starts at 1: accounts for the self loop every node gets
__global__ __launch_bounds__(256) void k_csr_zero(int* deg) {
  int i = blockIdx.x * 256 + threadIdx.x;
  if (i < NN) deg[i] = 1;
}

// count real edges only, 4 per thread (int4)
__global__ __launch_bounds__(256) void k_csr_count(const int* __restrict__ dst, int* __restrict__ deg) {
  int i = blockIdx.x * 256 + threadIdx.x;
  if (i >= NE / 4) return;
  int4 d4 = ((const int4*)dst)[i];
  atomicAdd(&deg[d4.x], 1);
  atomicAdd(&deg[d4.y], 1);
  atomicAdd(&deg[d4.z], 1);
  atomicAdd(&deg[d4.w], 1);
}

__global__ __launch_bounds__(SCAN_BLK) void k_scan1(const int* __restrict__ deg,
                                                    int* __restrict__ rowptr, int* __restrict__ part) {
  __shared__ int s[SCAN_BLK];
  int t = threadIdx.x;
  int g = blockIdx.x * SCAN_BLK + t;
  s[t] = (g < NN) ? deg[g] : 0;
  __syncthreads();
  for (int off = 1; off < SCAN_BLK; off <<= 1) {
    int u = (t >= off) ? s[t - off] : 0;
    __syncthreads();
    s[t] += u;
    __syncthreads();
  }
  if (g < NN) rowptr[g + 1] = s[t];
  if (t == SCAN_BLK - 1) part[blockIdx.x] = s[t];
}

// single-wave shfl scan over the 49 partials
__global__ void k_scan2(int* part) {
  int l = threadIdx.x & 63;
  int v = (l < NSCAN) ? part[l] : 0;
#pragma unroll
  for (int off = 1; off < 64; off <<= 1) {
    int u = __shfl_up(v, off);
    if (l >= off) v += u;
  }
  int ex = __shfl_up(v, 1);
  if (l == 0) ex = 0;
  if (l < NSCAN) part[l] = ex;
}

// finalize rowptr AND pre-init cursor[n] = rowptr[n]
__global__ __launch_bounds__(SCAN_BLK) void k_scan3(int* __restrict__ rowptr, int* __restrict__ cursor,
                                                    const int* __restrict__ part) {
  int t = threadIdx.x;
  int g = blockIdx.x * SCAN_BLK + t;
  if (g < NN) {
    int v = rowptr[g + 1] + part[blockIdx.x];
    rowptr[g + 1] = v;
    if (g + 1 < NN) cursor[g + 1] = v;
  }
  if (g == 0) { rowptr[0] = 0; cursor[0] = 0; }
}

// bucket bases from rowptr (bucket b = nodes [b*256, ...))
__global__ void k_binit(const int* __restrict__ rowptr, int* __restrict__ bcur) {
  int b = threadIdx.x + blockIdx.x * 256;
  if (b < NBUCK) {
    int nlo = b << 8; if (nlo > NN) nlo = NN;
    bcur[b] = rowptr[nlo];
  }
}

// pass B: group edges by bucket into staging, contiguous per-(block,bucket) runs
__global__ __launch_bounds__(256) void k_bucket(const int* __restrict__ src, const int* __restrict__ dst,
                                                int* __restrict__ bcur, unsigned* __restrict__ staging) {
  __shared__ int hist[NBUCK];
  __shared__ int base[NBUCK];
  const int t = threadIdx.x;
  const int e0 = blockIdx.x * BE;
  for (int b = t; b < NBUCK; b += 256) hist[b] = 0;
  __syncthreads();
  for (int j = t; j < BE; j += 256) {
    int i = e0 + j;
    if (i >= NT) break;
    int d = (i < NE) ? dst[i] : (i - NE);
    atomicAdd(&hist[d >> 8], 1);
  }
  __syncthreads();
  for (int b = t; b < NBUCK; b += 256) {
    int c = hist[b];
    base[b] = c ? atomicAdd(&bcur[b], c) : 0;
    hist[b] = 0;   // reuse as local cursor
  }
  __syncthreads();
  for (int j = t; j < BE; j += 256) {
    int i = e0 + j;
    if (i >= NT) break;
    int s, d;
    if (i < NE) { s = src[i]; d = dst[i]; } else { s = d = i - NE; }
    int b = d >> 8;
    int off = atomicAdd(&hist[b], 1);
    staging[base[b] + off] = ((unsigned)d << 16) | (unsigned)s;
  }
}

// pass C: per-bucket scatter to final CSR position (cursor+output window L2-resident)
__global__ __launch_bounds__(256) void k_scatter2(const unsigned* __restrict__ staging,
                                                  const int* __restrict__ rowptr,
                                                  int* __restrict__ cursor,
                                                  unsigned short* __restrict__ csr16) {
  const int b = blockIdx.x;
  int nlo = b << 8, nhi = nlo + 256;
  if (nhi > NN) nhi = NN;
  const int lo = rowptr[nlo], hi = rowptr[nhi];
  for (int k = lo + threadIdx.x; k < hi; k += 256) {
    unsigned e = staging[k];
    int d = (int)(e >> 16);
    int pos = atomicAdd(&cursor[d], 1);
    csr16[pos] = (unsigned short)(e & 0xFFFFu);
  }
}

// ================= layer 1 GEMM: x[50000x128] @ W1[128x128] -> bf16 h1u =================
__global__ __launch_bounds__(128, 2) void k_gemm1(
    const float* __restrict__ x, const float* __restrict__ W1,
    const float* __restrict__ asw_g, const float* __restrict__ adw_g,
    unsigned* __restrict__ h1u, float* __restrict__ as1, float* __restrict__ ad1) {
  __shared__ float sA[32][64];     // [k][row]
  __shared__ float sB[32][128];    // [k][col]
  const int t = threadIdx.x;
  const int tc = t & 15;           // 16 col groups x 8 cols
  const int tr = t >> 4;           // 8 row groups x 8 rows
  const int n0 = blockIdx.x * 64;

  float asw_t[8], adw_t[8];
#pragma unroll
  for (int j = 0; j < 8; ++j) { asw_t[j] = asw_g[tc * 8 + j]; adw_t[j] = adw_g[tc * 8 + j]; }

  float acc[8][8];
#pragma unroll
  for (int i = 0; i < 8; ++i)
#pragma unroll
    for (int j = 0; j < 8; ++j) acc[i][j] = 0.f;

  for (int kc = 0; kc < 128; kc += 32) {
#pragma unroll
    for (int f = 0; f < 4; ++f) {
      int id = t * 4 + f;
      int row = id >> 3;
      int q = id & 7;
      float4 v = make_float4(0.f, 0.f, 0.f, 0.f);
      int n = n0 + row;
      if (n < NN) v = *(const float4*)&x[(long long)n * 128 + kc + q * 4];
      sA[q * 4 + 0][row] = v.x; sA[q * 4 + 1][row] = v.y;
      sA[q * 4 + 2][row] = v.z; sA[q * 4 + 3][row] = v.w;
    }
#pragma unroll
    for (int f = 0; f < 8; ++f) {
      int id = t * 8 + f;
      int kk = id >> 5;
      int c4 = id & 31;
      *(float4*)&sB[kk][c4 * 4] = *(const float4*)&W1[(long long)(kc + kk) * 128 + c4 * 4];
    }
    __syncthreads();
#pragma unroll 4
    for (int kk = 0; kk < 32; ++kk) {
      float a[8], b[8];
      *(float4*)&a[0] = *(const float4*)&sA[kk][tr * 8];
      *(float4*)&a[4] = *(const float4*)&sA[kk][tr * 8 + 4];
      *(float4*)&b[0] = *(const float4*)&sB[kk][tc * 8];
      *(float4*)&b[4] = *(const float4*)&sB[kk][tc * 8 + 4];
#pragma unroll
      for (int i = 0; i < 8; ++i)
#pragma unroll
        for (int j = 0; j < 8; ++j) acc[i][j] += a[i] * b[j];
    }
    __syncthreads();
  }

  const int head = tc >> 3;
#pragma unroll
  for (int i = 0; i < 8; ++i) {
    int n = n0 + tr * 8 + i;
    if (n >= NN) break;
    uint4 pv;
    pv.x = pk_bf16x2(acc[i][0], acc[i][1]);
    pv.y = pk_bf16x2(acc[i][2], acc[i][3]);
    pv.z = pk_bf16x2(acc[i][4], acc[i][5]);
    pv.w = pk_bf16x2(acc[i][6], acc[i][7]);
    *(uint4*)&h1u[(long long)n * 64 + tc * 4] = pv;
    float vs = 0.f, vd = 0.f;
#pragma unroll
    for (int j = 0; j < 8; ++j) { vs += acc[i][j] * asw_t[j]; vd += acc[i][j] * adw_t[j]; }
    vs += __shfl_xor(vs, 1); vd += __shfl_xor(vd, 1);
    vs += __shfl_xor(vs, 2); vd += __shfl_xor(vd, 2);
    vs += __shfl_xor(vs, 4); vd += __shfl_xor(vd, 4);
    if ((tc & 7) == 0) { as1[n * 2 + head] = vs; ad1[n * 2 + head] = vd; }
  }
}

// ================= layer 1 fused GAT: LDS-broadcast weighted SpMM + mean + ELU =================
__global__ __launch_bounds__(256) void k_gat1(
    const int* __restrict__ rowptr, const unsigned short* __restrict__ csr16,
    const unsigned* __restrict__ h1u, const float2* __restrict__ as1,
    const float2* __restrict__ ad1, const float* __restrict__ b1,
    float* __restrict__ out1) {
  __shared__ float2 sw[4][2][64];     // [wave][head][slot] = {s_bits, w}
  const int t = threadIdx.x;
  const int wv = t >> 6;
  const int n = blockIdx.x * 4 + wv;
  if (n >= NN) return;
  const int p = t & 63;
  const int h = p >> 5;
  const int beg = rowptr[n], end = rowptr[n + 1];
  const int deg = end - beg;
  const float2 adn = ad1[n];

  float acc0 = 0.f, acc1 = 0.f;
  float inv;

  if (deg <= 64) {
    // ---- fast path: single chunk; lane p handles edge p ----
    int s = 0; float e0 = -1e30f, e1 = -1e30f;
    if (p < deg) {
      s = csr16[beg + p];
      float2 a = as1[s];
      e0 = a.x + adn.x; e0 = fmaxf(e0, 0.2f * e0);
      e1 = a.y + adn.y; e1 = fmaxf(e1, 0.2f * e1);
    }
    float m0 = e0, m1 = e1;
#pragma unroll
    for (int off = 1; off < 64; off <<= 1) {
      m0 = fmaxf(m0, __shfl_xor(m0, off));
      m1 = fmaxf(m1, __shfl_xor(m1, off));
    }
    float w0 = (p < deg) ? __expf(e0 - m0) : 0.f;
    float w1 = (p < deg) ? __expf(e1 - m1) : 0.f;
    float d0 = w0, d1 = w1;
#pragma unroll
    for (int off = 1; off < 64; off <<= 1) {
      d0 += __shfl_xor(d0, off);
      d1 += __shfl_xor(d1, off);
    }
    sw[wv][0][p] = make_float2(__int_as_float(s), w0);
    sw[wv][1][p] = make_float2(__int_as_float(s), w1);
    __builtin_amdgcn_wave_barrier();
    inv = 1.f / ((h ? d1 : d0) + 1e-16f);

    int j = 0;
    for (; j + 4 <= deg; j += 4) {
      float2 a0 = sw[wv][h][j], a1 = sw[wv][h][j + 1],
             a2 = sw[wv][h][j + 2], a3 = sw[wv][h][j + 3];
      unsigned v0 = h1u[(__float_as_int(a0.x) << 6) + p];
      unsigned v1 = h1u[(__float_as_int(a1.x) << 6) + p];
      unsigned v2 = h1u[(__float_as_int(a2.x) << 6) + p];
      unsigned v3 = h1u[(__float_as_int(a3.x) << 6) + p];
      acc0 += a0.y * __uint_as_float(v0 << 16); acc1 += a0.y * __uint_as_float(v0 & 0xFFFF0000u);
      acc0 += a1.y * __uint_as_float(v1 << 16); acc1 += a1.y * __uint_as_float(v1 & 0xFFFF0000u);
      acc0 += a2.y * __uint_as_float(v2 << 16); acc1 += a2.y * __uint_as_float(v2 & 0xFFFF0000u);
      acc0 += a3.y * __uint_as_float(v3 << 16); acc1 += a3.y * __uint_as_float(v3 & 0xFFFF0000u);
    }
    for (; j < deg; ++j) {
      float2 a = sw[wv][h][j];
      unsigned v = h1u[(__float_as_int(a.x) << 6) + p];
      acc0 += a.y * __uint_as_float(v << 16); acc1 += a.y * __uint_as_float(v & 0xFFFF0000u);
    }
  } else {
    // ---- slow path (deg > 64) ----
    float m0 = -1e30f, d0 = 0.f, m1 = -1e30f, d1 = 0.f;
    for (int k = beg + p; k < end; k += 64) {
      float2 a = as1[csr16[k]];
      float e0 = a.x + adn.x; e0 = fmaxf(e0, 0.2f * e0);
      float e1 = a.y + adn.y; e1 = fmaxf(e1, 0.2f * e1);
      if (e0 > m0) { d0 *= __expf(m0 - e0); m0 = e0; }
      d0 += __expf(e0 - m0);
      if (e1 > m1) { d1 *= __expf(m1 - e1); m1 = e1; }
      d1 += __expf(e1 - m1);
    }
#pragma unroll
    for (int off = 1; off < 64; off <<= 1) {
      float mo = __shfl_xor(m0, off), dd = __shfl_xor(d0, off);
      float mn = fmaxf(m0, mo);
      d0 = d0 * __expf(m0 - mn) + dd * __expf(mo - mn);
      m0 = mn;
      mo = __shfl_xor(m1, off); dd = __shfl_xor(d1, off);
      mn = fmaxf(m1, mo);
      d1 = d1 * __expf(m1 - mn) + dd * __expf(mo - mn);
      m1 = mn;
    }
    inv = 1.f / ((h ? d1 : d0) + 1e-16f);
    for (int c0 = beg; c0 < end; c0 += 64) {
      int nc = end - c0; if (nc > 64) nc = 64;
      int s = 0; float w0 = 0.f, w1 = 0.f;
      if (p < nc) {
        s = csr16[c0 + p];
        float2 a = as1[s];
        float e0 = a.x + adn.x; e0 = fmaxf(e0, 0.2f * e0);
        float e1 = a.y + adn.y; e1 = fmaxf(e1, 0.2f * e1);
        w0 = __expf(e0 - m0);
        w1 = __expf(e1 - m1);
      }
      __builtin_amdgcn_wave_barrier();
      sw[wv][0][p] = make_float2(__int_as_float(s), w0);
      sw[wv][1][p] = make_float2(__int_as_float(s), w1);
      __builtin_amdgcn_wave_barrier();
      for (int j = 0; j < nc; ++j) {
        float2 a = sw[wv][h][j];
        unsigned v = h1u[(__float_as_int(a.x) << 6) + p];
        acc0 += a.y * __uint_as_float(v << 16); acc1 += a.y * __uint_as_float(v & 0xFFFF0000u);
      }
      __builtin_amdgcn_wave_barrier();
    }
  }

  acc0 *= inv; acc1 *= inv;
  acc0 += __shfl_xor(acc0, 32);
  acc1 += __shfl_xor(acc1, 32);
  if (p < 32) {
    float u0 = 0.5f * acc0 + b1[2 * p];
    float u1 = 0.5f * acc1 + b1[2 * p + 1];
    u0 = u0 > 0.f ? u0 : expm1f(u0);
    u1 = u1 > 0.f ? u1 : expm1f(u1);
    *(float2*)&out1[(long long)n * 64 + 2 * p] = make_float2(u0, u1);
  }
}

// ================= layer 2 GEMM: out1[50000x64] @ W2[64x64] -> bf16 h2u =================
__global__ __launch_bounds__(128, 2) void k_gemm2(
    const float* __restrict__ in, const float* __restrict__ W2,
    const float* __restrict__ asw_g, const float* __restrict__ adw_g,
    unsigned* __restrict__ h2u, float* __restrict__ as2, float* __restrict__ ad2) {
  __shared__ float sB[64][64];
  __shared__ float sA[32][132];
  const int t = threadIdx.x;
  const int tc = t & 7;
  const int tr = t >> 3;
  const int n0 = blockIdx.x * 128;

#pragma unroll
  for (int f = 0; f < 8; ++f) {
    int id = t * 8 + f;
    int kk = id >> 4;
    int c4 = id & 15;
    *(float4*)&sB[kk][c4 * 4] = *(const float4*)&W2[kk * 64 + c4 * 4];
  }

  float asw_t[8], adw_t[8];
#pragma unroll
  for (int j = 0; j < 8; ++j) { asw_t[j] = asw_g[tc * 8 + j]; adw_t[j] = adw_g[tc * 8 + j]; }

  float acc[8][8];
#pragma unroll
  for (int i = 0; i < 8; ++i)
#pragma unroll
    for (int j = 0; j < 8; ++j) acc[i][j] = 0.f;

  for (int kc = 0; kc < 64; kc += 32) {
#pragma unroll
    for (int f = 0; f < 8; ++f) {
      int id = f * 128 + t;
      int row = id >> 3;
      int q = id & 7;
      float4 v = make_float4(0.f, 0.f, 0.f, 0.f);
      int n = n0 + row;
      if (n < NN) v = *(const float4*)&in[(long long)n * 64 + kc + q * 4];
      sA[q * 4 + 0][row] = v.x; sA[q * 4 + 1][row] = v.y;
      sA[q * 4 + 2][row] = v.z; sA[q * 4 + 3][row] = v.w;
    }
    __syncthreads();
#pragma unroll 4
    for (int kk = 0; kk < 32; ++kk) {
      float a[8], b[8];
      *(float4*)&a[0] = *(const float4*)&sA[kk][tr * 8];
      *(float4*)&a[4] = *(const float4*)&sA[kk][tr * 8 + 4];
      *(float4*)&b[0] = *(const float4*)&sB[kc + kk][tc * 8];
      *(float4*)&b[4] = *(const float4*)&sB[kc + kk][tc * 8 + 4];
#pragma unroll
      for (int i = 0; i < 8; ++i)
#pragma unroll
        for (int j = 0; j < 8; ++j) acc[i][j] += a[i] * b[j];
    }
    __syncthreads();
  }

#pragma unroll
  for (int i = 0; i < 8; ++i) {
    int n = n0 + tr * 8 + i;
    if (n >= NN) break;
    uint4 pv;
    pv.x = pk_bf16x2(acc[i][0], acc[i][1]);
    pv.y = pk_bf16x2(acc[i][2], acc[i][3]);
    pv.z = pk_bf16x2(acc[i][4], acc[i][5]);
    pv.w = pk_bf16x2(acc[i][6], acc[i][7]);
    *(uint4*)&h2u[(long long)n * 32 + tc * 4] = pv;
    float vs = 0.f, vd = 0.f;
#pragma unroll
    for (int j = 0; j < 8; ++j) { vs += acc[i][j] * asw_t[j]; vd += acc[i][j] * adw_t[j]; }
    vs += __shfl_xor(vs, 1); vd += __shfl_xor(vd, 1);
    vs += __shfl_xor(vs, 2); vd += __shfl_xor(vd, 2);
    vs += __shfl_xor(vs, 4); vd += __shfl_xor(vd, 4);
    if (tc == 0) { as2[n] = vs; ad2[n] = vd; }
  }
}

// ================= layer 2 fused GAT + classifier + log_softmax =================
__global__ __launch_bounds__(256) void k_gat2(
    const int* __restrict__ rowptr, const unsigned short* __restrict__ csr16,
    const unsigned* __restrict__ h2u, const float* __restrict__ as2,
    const float* __restrict__ ad2, const float* __restrict__ b2,
    const float* __restrict__ Wc, const float* __restrict__ bc,
    float* __restrict__ out) {
  __shared__ float2 sw[4][64];        // [wave][slot] = {s_bits, w}
  const int t = threadIdx.x;
  const int wv = t >> 6;
  const int n = blockIdx.x * 4 + wv;
  if (n >= NN) return;
  const int p = t & 63;
  const int half = p >> 5;
  const int q = p & 31;
  const int beg = rowptr[n], end = rowptr[n + 1];
  const int deg = end - beg;
  const float adn = ad2[n];

  float acc0 = 0.f, acc1 = 0.f;
  float inv;

  if (deg <= 64) {
    // ---- fast path ----
    int s = 0; float e = -1e30f;
    if (p < deg) {
      s = csr16[beg + p];
      e = as2[s] + adn;
      e = fmaxf(e, 0.2f * e);
    }
    float m = e;
#pragma unroll
    for (int off = 1; off < 64; off <<= 1) m = fmaxf(m, __shfl_xor(m, off));
    float w = (p < deg) ? __expf(e - m) : 0.f;
    float d = w;
#pragma unroll
    for (int off = 1; off < 64; off <<= 1) d += __shfl_xor(d, off);
    sw[wv][p] = make_float2(__int_as_float(s), w);
    __builtin_amdgcn_wave_barrier();
    inv = 1.f / (d + 1e-16f);

    int niter = (deg + 1) >> 1;
    int i = 0;
    for (; i + 2 <= niter; i += 2) {
      float2 a0 = sw[wv][2 * i + half];
      float2 a1 = sw[wv][2 * i + 2 + half];
      unsigned v0 = h2u[(__float_as_int(a0.x) << 5) + q];
      unsigned v1 = h2u[(__float_as_int(a1.x) << 5) + q];
      acc0 += a0.y * __uint_as_float(v0 << 16); acc1 += a0.y * __uint_as_float(v0 & 0xFFFF0000u);
      acc0 += a1.y * __uint_as_float(v1 << 16); acc1 += a1.y * __uint_as_float(v1 & 0xFFFF0000u);
    }
    if (i < niter) {
      float2 a = sw[wv][2 * i + half];
      unsigned v = h2u[(__float_as_int(a.x) << 5) + q];
      acc0 += a.y * __uint_as_float(v << 16); acc1 += a.y * __uint_as_float(v & 0xFFFF0000u);
    }
  } else {
    // ---- slow path ----
    float m = -1e30f, d = 0.f;
    for (int k = beg + p; k < end; k += 64) {
      float e = as2[csr16[k]] + adn;
      e = fmaxf(e, 0.2f * e);
      if (e > m) { d *= __expf(m - e); m = e; }
      d += __expf(e - m);
    }
#pragma unroll
    for (int off = 1; off < 64; off <<= 1) {
      float mo = __shfl_xor(m, off), dd = __shfl_xor(d, off);
      float mn = fmaxf(m, mo);
      d = d * __expf(m - mn) + dd * __expf(mo - mn);
      m = mn;
    }
    inv = 1.f / (d + 1e-16f);
    for (int c0 = beg; c0 < end; c0 += 64) {
      int nc = end - c0; if (nc > 64) nc = 64;
      int s = 0; float w = 0.f;
      if (p < nc) {
        s = csr16[c0 + p];
        float e = as2[s] + adn;
        e = fmaxf(e, 0.2f * e);
        w = __expf(e - m);
      }
      __builtin_amdgcn_wave_barrier();
      sw[wv][p] = make_float2(__int_as_float(s), w);
      __builtin_amdgcn_wave_barrier();
      int niter = (nc + 1) >> 1;
      for (int i = 0; i < niter; ++i) {
        int j = 2 * i + half;
        float2 a = sw[wv][j < nc ? j : 0];
        float wj = (j < nc) ? a.y : 0.f;
        unsigned v = h2u[(__float_as_int(a.x) << 5) + q];
        acc0 += wj * __uint_as_float(v << 16); acc1 += wj * __uint_as_float(v & 0xFFFF0000u);
      }
      __builtin_amdgcn_wave_barrier();
    }
  }

  acc0 += __shfl_xor(acc0, 32);
  acc1 += __shfl_xor(acc1, 32);
  float v0 = acc0 * inv + b2[2 * q];
  float v1 = acc1 * inv + b2[2 * q + 1];
  v0 = v0 > 0.f ? v0 : expm1f(v0);
  v1 = v1 > 0.f ? v1 : expm1f(v1);
  float l0 = v0 * Wc[4 * q] + v1 * Wc[4 * q + 2];
  float l1 = v0 * Wc[4 * q + 1] + v1 * Wc[4 * q + 3];
#pragma unroll
  for (int off = 1; off < 32; off <<= 1) {
    l0 += __shfl_xor(l0, off);
    l1 += __shfl_xor(l1, off);
  }
  if (p == 0) {
    l0 += bc[0]; l1 += bc[1];
    float mx = fmaxf(l0, l1);
    float lse = mx + logf(expf(l0 - mx) + expf(l1 - mx));
    out[n * 2] = l0 - lse;
    out[n * 2 + 1] = l1 - lse;
  }
}

extern "C" void kernel_launch(void* const* d_in, const int* in_sizes, int n_in,
                              void* d_out, int out_size, void* d_ws, size_t ws_size,
                              hipStream_t stream) {
  const float* x    = (const float*)d_in[0];
  const int*   ei   = (const int*)d_in[1];
  const float* W1   = (const float*)d_in[2];
  const float* as1w = (const float*)d_in[3];
  const float* ad1w = (const float*)d_in[4];
  const float* b1   = (const float*)d_in[5];
  const float* W2   = (const float*)d_in[6];
  const float* as2w = (const float*)d_in[7];
  const float* ad2w = (const float*)d_in[8];
  const float* b2   = (const float*)d_in[9];
  const float* Wc   = (const float*)d_in[10];
  const float* bc   = (const float*)d_in[11];
  float* out = (float*)d_out;

  const int* src = ei;
  const int* dst = ei + NE;

  // ---- workspace layout ----
  char* p = (char*)d_ws;
  unsigned* h1u = (unsigned*)p; p += sizeof(unsigned) * (long long)NN * 64;  // bf16x2 h1
  unsigned* h2u = (unsigned*)p; p += sizeof(unsigned) * (long long)NN * 32;  // bf16x2 h2
  float* out1 = (float*)p; p += sizeof(float) * (long long)NN * 64;
  float* as1  = (float*)p; p += sizeof(float) * NN * 2;
  float* ad1  = (float*)p; p += sizeof(float) * NN * 2;
  float* as2  = (float*)p; p += sizeof(float) * NN;
  float* ad2  = (float*)p; p += sizeof(float) * NN;
  int* deg     = (int*)p; p += sizeof(int) * NN;
  int* cursor  = (int*)p; p += sizeof(int) * NN;
  int* rowptr  = (int*)p; p += sizeof(int) * (NN + 1);
  int* part    = (int*)p; p += sizeof(int) * ((NSCAN + 63) & ~63);
  int* bcur    = (int*)p; p += sizeof(int) * ((NBUCK + 63) & ~63);
  unsigned* staging = (unsigned*)p; p += sizeof(unsigned) * (long long)NT;
  unsigned short* csr16 = (unsigned short*)p; p += sizeof(unsigned short) * (long long)NT;

  // ---- CSR build (graph shared by both layers) ----
  k_csr_zero<<<(NN + 255) / 256, 256, 0, stream>>>(deg);
  k_csr_count<<<(NE / 4 + 255) / 256, 256, 0, stream>>>(dst, deg);
  k_scan1<<<NSCAN, SCAN_BLK, 0, stream>>>(deg, rowptr, part);
  k_scan2<<<1, 64, 0, stream>>>(part);
  k_scan3<<<NSCAN, SCAN_BLK, 0, stream>>>(rowptr, cursor, part);
  k_binit<<<1, 256, 0, stream>>>(rowptr, bcur);
  k_bucket<<<NBLK_B, 256, 0, stream>>>(src, dst, bcur, staging);
  k_scatter2<<<NBUCK, 256, 0, stream>>>(staging, rowptr, cursor, csr16);

  // ---- layer 1 ----
  k_gemm1<<<(NN + 63) / 64, 128, 0, stream>>>(x, W1, as1w, ad1w, h1u, as1, ad1);
  k_gat1<<<(NN + 3) / 4, 256, 0, stream>>>(rowptr, csr16, h1u, (const float2*)as1,
                                           (const float2*)ad1, b1, out1);

  // ---- layer 2 ----
  k_gemm2<<<(NN + 127) / 128, 128, 0, stream>>>(out1, W2, as2w, ad2w, h2u, as2, ad2);
  k_gat2<<<(NN + 3) / 4, 256, 0, stream>>>(rowptr, csr16, h2u, as2, ad2, b2, Wc, bc, out);
}

// Round 9
// 192.477 us; speedup vs baseline: 1.5148x; 1.1898x over previous
//
#include <hip/hip_runtime.h>
#include <math.h>

#define NN 50000          // nodes
#define NE 800000         // edges (without self loops)
#define NT (NE + NN)      // edges incl self loops
#define SCAN_BLK 1024
#define NSCAN ((NN + SCAN_BLK - 1) / SCAN_BLK)   // 49
#define NBUCK 196         // dst>>8 buckets (256 nodes each)
#define BE 8192           // edges per bucket-pass block
#define NBLK_B ((NT + BE - 1) / BE)              // 104

typedef short bf16x8 __attribute__((ext_vector_type(8)));
typedef float f32x4 __attribute__((ext_vector_type(4)));
union U16x8 { uint4 u; bf16x8 s; };

// pack two fp32 -> bf16x2 (RNE)
__device__ __forceinline__ unsigned pk_bf16x2(float x, float y) {
  unsigned ux = __float_as_uint(x); ux = ux + 0x7FFFu + ((ux >> 16) & 1u);
  unsigned uy = __float_as_uint(y); uy = uy + 0x7FFFu + ((uy >> 16) & 1u);
  return (ux >> 16) | (uy & 0xFFFF0000u);
}
__device__ __forceinline__ unsigned short bf16_1(float x) {
  unsigned u = __float_as_uint(x); u = u + 0x7FFFu + ((u >> 16) & 1u);
  return (unsigned short)(u >> 16);
}

// ================= weight fragment prep (bf16, MFMA B-operand order) =================
// B-frag for 16x16x32: lane l supplies B[k=8*(l>>4)+j][col=l&15]; frag id = ct*KT+kt
__global__ __launch_bounds__(256) void k_prep(const float* __restrict__ W1, const float* __restrict__ W2,
                                              unsigned short* __restrict__ w1f,
                                              unsigned short* __restrict__ w2f) {
  int i = blockIdx.x * 256 + threadIdx.x;
  if (i < 128 * 128) {
    int k = i >> 7, col = i & 127;
    int ct = col >> 4, kt = k >> 5, lane = (((k >> 3) & 3) << 4) | (col & 15), j = k & 7;
    w1f[(((ct << 2) | kt) * 64 + lane) * 8 + j] = bf16_1(W1[i]);
  } else if (i < 128 * 128 + 64 * 64) {
    int e = i - 128 * 128;
    int k = e >> 6, col = e & 63;
    int ct = col >> 4, kt = k >> 5, lane = (((k >> 3) & 3) << 4) | (col & 15), j = k & 7;
    w2f[(((ct << 1) | kt) * 64 + lane) * 8 + j] = bf16_1(W2[e]);
  }
}

// ================= CSR build =================
__global__ __launch_bounds__(256) void k_csr_zero(int* deg) {
  int i = blockIdx.x * 256 + threadIdx.x;
  if (i < NN) deg[i] = 1;          // self loop
}

__global__ __launch_bounds__(256) void k_csr_count(const int* __restrict__ dst, int* __restrict__ deg) {
  int i = blockIdx.x * 256 + threadIdx.x;
  if (i >= NE / 4) return;
  int4 d4 = ((const int4*)dst)[i];
  atomicAdd(&deg[d4.x], 1);
  atomicAdd(&deg[d4.y], 1);
  atomicAdd(&deg[d4.z], 1);
  atomicAdd(&deg[d4.w], 1);
}

__global__ __launch_bounds__(SCAN_BLK) void k_scan1(const int* __restrict__ deg,
                                                    int* __restrict__ rowptr, int* __restrict__ part) {
  __shared__ int s[SCAN_BLK];
  int t = threadIdx.x;
  int g = blockIdx.x * SCAN_BLK + t;
  s[t] = (g < NN) ? deg[g] : 0;
  __syncthreads();
  for (int off = 1; off < SCAN_BLK; off <<= 1) {
    int u = (t >= off) ? s[t - off] : 0;
    __syncthreads();
    s[t] += u;
    __syncthreads();
  }
  if (g < NN) rowptr[g + 1] = s[t];
  if (t == SCAN_BLK - 1) part[blockIdx.x] = s[t];
}

__global__ void k_scan2(int* part) {
  int l = threadIdx.x & 63;
  int v = (l < NSCAN) ? part[l] : 0;
#pragma unroll
  for (int off = 1; off < 64; off <<= 1) {
    int u = __shfl_up(v, off);
    if (l >= off) v += u;
  }
  int ex = __shfl_up(v, 1);
  if (l == 0) ex = 0;
  if (l < NSCAN) part[l] = ex;
}

__global__ __launch_bounds__(SCAN_BLK) void k_scan3(int* __restrict__ rowptr, int* __restrict__ cursor,
                                                    const int* __restrict__ part) {
  int t = threadIdx.x;
  int g = blockIdx.x * SCAN_BLK + t;
  if (g < NN) {
    int v = rowptr[g + 1] + part[blockIdx.x];
    rowptr[g + 1] = v;
    if (g + 1 < NN) cursor[g + 1] = v;
  }
  if (g == 0) { rowptr[0] = 0; cursor[0] = 0; }
}

__global__ void k_binit(const int* __restrict__ rowptr, int* __restrict__ bcur) {
  int b = threadIdx.x + blockIdx.x * 256;
  if (b < NBUCK) {
    int nlo = b << 8; if (nlo > NN) nlo = NN;
    bcur[b] = rowptr[nlo];
  }
}

__global__ __launch_bounds__(256) void k_bucket(const int* __restrict__ src, const int* __restrict__ dst,
                                                int* __restrict__ bcur, unsigned* __restrict__ staging) {
  __shared__ int hist[NBUCK];
  __shared__ int base[NBUCK];
  const int t = threadIdx.x;
  const int e0 = blockIdx.x * BE;
  for (int b = t; b < NBUCK; b += 256) hist[b] = 0;
  __syncthreads();
  for (int j = t; j < BE; j += 256) {
    int i = e0 + j;
    if (i >= NT) break;
    int d = (i < NE) ? dst[i] : (i - NE);
    atomicAdd(&hist[d >> 8], 1);
  }
  __syncthreads();
  for (int b = t; b < NBUCK; b += 256) {
    int c = hist[b];
    base[b] = c ? atomicAdd(&bcur[b], c) : 0;
    hist[b] = 0;
  }
  __syncthreads();
  for (int j = t; j < BE; j += 256) {
    int i = e0 + j;
    if (i >= NT) break;
    int s, d;
    if (i < NE) { s = src[i]; d = dst[i]; } else { s = d = i - NE; }
    int b = d >> 8;
    int off = atomicAdd(&hist[b], 1);
    staging[base[b] + off] = ((unsigned)d << 16) | (unsigned)s;
  }
}

__global__ __launch_bounds__(256) void k_scatter2(const unsigned* __restrict__ staging,
                                                  const int* __restrict__ rowptr,
                                                  int* __restrict__ cursor,
                                                  unsigned short* __restrict__ csr16) {
  const int b = blockIdx.x;
  int nlo = b << 8, nhi = nlo + 256;
  if (nhi > NN) nhi = NN;
  const int lo = rowptr[nlo], hi = rowptr[nhi];
  for (int k = lo + threadIdx.x; k < hi; k += 256) {
    unsigned e = staging[k];
    int d = (int)(e >> 16);
    int pos = atomicAdd(&cursor[d], 1);
    csr16[pos] = (unsigned short)(e & 0xFFFFu);
  }
}

// ================= layer 1 MFMA GEMM: x[50000x128] @ W1[128x128] -> bf16 h1b =================
// 256 thr = 4 waves; wave computes 16 rows x 128 cols via 8 col-tiles x 4 k-steps.
// No LDS: A frags direct from x (+cvt), B frags from w1f (L2-broadcast).
__global__ __launch_bounds__(256) void k_gemm1(
    const float* __restrict__ x, const unsigned short* __restrict__ w1f,
    const float* __restrict__ asw_g, const float* __restrict__ adw_g,
    unsigned short* __restrict__ h1b, float* __restrict__ as1, float* __restrict__ ad1) {
  const int t = threadIdx.x;
  const int wid = t >> 6, l = t & 63;
  const int lr = l & 15, lg = l >> 4;
  const int arow = blockIdx.x * 64 + wid * 16 + lr;   // A row this lane feeds
  const bool aok = arow < NN;

  float asw_t[8], adw_t[8];
#pragma unroll
  for (int ct = 0; ct < 8; ++ct) {
    asw_t[ct] = asw_g[ct * 16 + lr];
    adw_t[ct] = adw_g[ct * 16 + lr];
  }

  f32x4 acc[8];
#pragma unroll
  for (int ct = 0; ct < 8; ++ct) acc[ct] = (f32x4){0.f, 0.f, 0.f, 0.f};

#pragma unroll
  for (int kt = 0; kt < 4; ++kt) {
    U16x8 a;
    if (aok) {
      const float* xp = &x[(long long)arow * 128 + kt * 32 + lg * 8];
      float4 f0 = *(const float4*)xp;
      float4 f1 = *(const float4*)(xp + 4);
      a.u.x = pk_bf16x2(f0.x, f0.y); a.u.y = pk_bf16x2(f0.z, f0.w);
      a.u.z = pk_bf16x2(f1.x, f1.y); a.u.w = pk_bf16x2(f1.z, f1.w);
    } else {
      a.u = make_uint4(0, 0, 0, 0);
    }
#pragma unroll
    for (int ct = 0; ct < 8; ++ct) {
      U16x8 b;
      b.u = *(const uint4*)&w1f[(((ct << 2) | kt) * 64 + l) * 8];
      acc[ct] = __builtin_amdgcn_mfma_f32_16x16x32_bf16(a.s, b.s, acc[ct], 0, 0, 0);
    }
  }

  // D: lane holds rows 4*lg+reg, col ct*16+lr
  const int gr0 = blockIdx.x * 64 + wid * 16 + lg * 4;
#pragma unroll
  for (int reg = 0; reg < 4; ++reg) {
    int grow = gr0 + reg;
    bool ok = grow < NN;
    float s0 = 0.f, s1 = 0.f, d0 = 0.f, d1 = 0.f;
#pragma unroll
    for (int ct = 0; ct < 8; ++ct) {
      float v = acc[ct][reg];
      if (ok) h1b[(long long)grow * 128 + ct * 16 + lr] = bf16_1(v);
      if (ct < 4) { s0 += v * asw_t[ct]; d0 += v * adw_t[ct]; }
      else        { s1 += v * asw_t[ct]; d1 += v * adw_t[ct]; }
    }
#pragma unroll
    for (int off = 1; off < 16; off <<= 1) {
      s0 += __shfl_xor(s0, off); d0 += __shfl_xor(d0, off);
      s1 += __shfl_xor(s1, off); d1 += __shfl_xor(d1, off);
    }
    if (ok && lr == 0) {
      as1[grow * 2] = s0; as1[grow * 2 + 1] = s1;
      ad1[grow * 2] = d0; ad1[grow * 2 + 1] = d1;
    }
  }
}

// ================= layer 1 fused GAT: LDS-broadcast weighted SpMM + mean + ELU -> bf16 out1b ====
__global__ __launch_bounds__(256) void k_gat1(
    const int* __restrict__ rowptr, const unsigned short* __restrict__ csr16,
    const unsigned* __restrict__ h1u, const float2* __restrict__ as1,
    const float2* __restrict__ ad1, const float* __restrict__ b1,
    unsigned* __restrict__ out1b) {
  __shared__ float2 sw[4][2][64];
  const int t = threadIdx.x;
  const int wv = t >> 6;
  const int n = blockIdx.x * 4 + wv;
  if (n >= NN) return;
  const int p = t & 63;
  const int h = p >> 5;
  const int beg = rowptr[n], end = rowptr[n + 1];
  const int deg = end - beg;
  const float2 adn = ad1[n];

  float acc0 = 0.f, acc1 = 0.f;
  float inv;

  if (deg <= 64) {
    int s = 0; float e0 = -1e30f, e1 = -1e30f;
    if (p < deg) {
      s = csr16[beg + p];
      float2 a = as1[s];
      e0 = a.x + adn.x; e0 = fmaxf(e0, 0.2f * e0);
      e1 = a.y + adn.y; e1 = fmaxf(e1, 0.2f * e1);
    }
    float m0 = e0, m1 = e1;
#pragma unroll
    for (int off = 1; off < 64; off <<= 1) {
      m0 = fmaxf(m0, __shfl_xor(m0, off));
      m1 = fmaxf(m1, __shfl_xor(m1, off));
    }
    float w0 = (p < deg) ? __expf(e0 - m0) : 0.f;
    float w1 = (p < deg) ? __expf(e1 - m1) : 0.f;
    float d0 = w0, d1 = w1;
#pragma unroll
    for (int off = 1; off < 64; off <<= 1) {
      d0 += __shfl_xor(d0, off);
      d1 += __shfl_xor(d1, off);
    }
    sw[wv][0][p] = make_float2(__int_as_float(s), w0);
    sw[wv][1][p] = make_float2(__int_as_float(s), w1);
    __builtin_amdgcn_wave_barrier();
    inv = 1.f / ((h ? d1 : d0) + 1e-16f);

    int j = 0;
    for (; j + 4 <= deg; j += 4) {
      float2 a0 = sw[wv][h][j], a1 = sw[wv][h][j + 1],
             a2 = sw[wv][h][j + 2], a3 = sw[wv][h][j + 3];
      unsigned v0 = h1u[(__float_as_int(a0.x) << 6) + p];
      unsigned v1 = h1u[(__float_as_int(a1.x) << 6) + p];
      unsigned v2 = h1u[(__float_as_int(a2.x) << 6) + p];
      unsigned v3 = h1u[(__float_as_int(a3.x) << 6) + p];
      acc0 += a0.y * __uint_as_float(v0 << 16); acc1 += a0.y * __uint_as_float(v0 & 0xFFFF0000u);
      acc0 += a1.y * __uint_as_float(v1 << 16); acc1 += a1.y * __uint_as_float(v1 & 0xFFFF0000u);
      acc0 += a2.y * __uint_as_float(v2 << 16); acc1 += a2.y * __uint_as_float(v2 & 0xFFFF0000u);
      acc0 += a3.y * __uint_as_float(v3 << 16); acc1 += a3.y * __uint_as_float(v3 & 0xFFFF0000u);
    }
    for (; j < deg; ++j) {
      float2 a = sw[wv][h][j];
      unsigned v = h1u[(__float_as_int(a.x) << 6) + p];
      acc0 += a.y * __uint_as_float(v << 16); acc1 += a.y * __uint_as_float(v & 0xFFFF0000u);
    }
  } else {
    float m0 = -1e30f, d0 = 0.f, m1 = -1e30f, d1 = 0.f;
    for (int k = beg + p; k < end; k += 64) {
      float2 a = as1[csr16[k]];
      float e0 = a.x + adn.x; e0 = fmaxf(e0, 0.2f * e0);
      float e1 = a.y + adn.y; e1 = fmaxf(e1, 0.2f * e1);
      if (e0 > m0) { d0 *= __expf(m0 - e0); m0 = e0; }
      d0 += __expf(e0 - m0);
      if (e1 > m1) { d1 *= __expf(m1 - e1); m1 = e1; }
      d1 += __expf(e1 - m1);
    }
#pragma unroll
    for (int off = 1; off < 64; off <<= 1) {
      float mo = __shfl_xor(m0, off), dd = __shfl_xor(d0, off);
      float mn = fmaxf(m0, mo);
      d0 = d0 * __expf(m0 - mn) + dd * __expf(mo - mn);
      m0 = mn;
      mo = __shfl_xor(m1, off); dd = __shfl_xor(d1, off);
      mn = fmaxf(m1, mo);
      d1 = d1 * __expf(m1 - mn) + dd * __expf(mo - mn);
      m1 = mn;
    }
    inv = 1.f / ((h ? d1 : d0) + 1e-16f);
    for (int c0 = beg; c0 < end; c0 += 64) {
      int nc = end - c0; if (nc > 64) nc = 64;
      int s = 0; float w0 = 0.f, w1 = 0.f;
      if (p < nc) {
        s = csr16[c0 + p];
        float2 a = as1[s];
        float e0 = a.x + adn.x; e0 = fmaxf(e0, 0.2f * e0);
        float e1 = a.y + adn.y; e1 = fmaxf(e1, 0.2f * e1);
        w0 = __expf(e0 - m0);
        w1 = __expf(e1 - m1);
      }
      __builtin_amdgcn_wave_barrier();
      sw[wv][0][p] = make_float2(__int_as_float(s), w0);
      sw[wv][1][p] = make_float2(__int_as_float(s), w1);
      __builtin_amdgcn_wave_barrier();
      for (int j = 0; j < nc; ++j) {
        float2 a = sw[wv][h][j];
        unsigned v = h1u[(__float_as_int(a.x) << 6) + p];
        acc0 += a.y * __uint_as_float(v << 16); acc1 += a.y * __uint_as_float(v & 0xFFFF0000u);
      }
      __builtin_amdgcn_wave_barrier();
    }
  }

  acc0 *= inv; acc1 *= inv;
  acc0 += __shfl_xor(acc0, 32);
  acc1 += __shfl_xor(acc1, 32);
  if (p < 32) {
    float u0 = 0.5f * acc0 + b1[2 * p];
    float u1 = 0.5f * acc1 + b1[2 * p + 1];
    u0 = u0 > 0.f ? u0 : expm1f(u0);
    u1 = u1 > 0.f ? u1 : expm1f(u1);
    out1b[n * 32 + p] = pk_bf16x2(u0, u1);
  }
}

// ================= layer 2 MFMA GEMM: out1b[50000x64 bf16] @ W2[64x64] -> bf16 h2b =================
__global__ __launch_bounds__(256) void k_gemm2(
    const unsigned short* __restrict__ in_b, const unsigned short* __restrict__ w2f,
    const float* __restrict__ asw_g, const float* __restrict__ adw_g,
    unsigned short* __restrict__ h2b, float* __restrict__ as2, float* __restrict__ ad2) {
  const int t = threadIdx.x;
  const int wid = t >> 6, l = t & 63;
  const int lr = l & 15, lg = l >> 4;
  const int arow = blockIdx.x * 64 + wid * 16 + lr;
  const bool aok = arow < NN;

  float asw_t[4], adw_t[4];
#pragma unroll
  for (int ct = 0; ct < 4; ++ct) {
    asw_t[ct] = asw_g[ct * 16 + lr];
    adw_t[ct] = adw_g[ct * 16 + lr];
  }

  f32x4 acc[4];
#pragma unroll
  for (int ct = 0; ct < 4; ++ct) acc[ct] = (f32x4){0.f, 0.f, 0.f, 0.f};

#pragma unroll
  for (int kt = 0; kt < 2; ++kt) {
    U16x8 a;
    if (aok) a.u = *(const uint4*)&in_b[(long long)arow * 64 + kt * 32 + lg * 8];
    else a.u = make_uint4(0, 0, 0, 0);
#pragma unroll
    for (int ct = 0; ct < 4; ++ct) {
      U16x8 b;
      b.u = *(const uint4*)&w2f[(((ct << 1) | kt) * 64 + l) * 8];
      acc[ct] = __builtin_amdgcn_mfma_f32_16x16x32_bf16(a.s, b.s, acc[ct], 0, 0, 0);
    }
  }

  const int gr0 = blockIdx.x * 64 + wid * 16 + lg * 4;
#pragma unroll
  for (int reg = 0; reg < 4; ++reg) {
    int grow = gr0 + reg;
    bool ok = grow < NN;
    float s0 = 0.f, d0 = 0.f;
#pragma unroll
    for (int ct = 0; ct < 4; ++ct) {
      float v = acc[ct][reg];
      if (ok) h2b[(long long)grow * 64 + ct * 16 + lr] = bf16_1(v);
      s0 += v * asw_t[ct]; d0 += v * adw_t[ct];
    }
#pragma unroll
    for (int off = 1; off < 16; off <<= 1) {
      s0 += __shfl_xor(s0, off); d0 += __shfl_xor(d0, off);
    }
    if (ok && lr == 0) { as2[grow] = s0; ad2[grow] = d0; }
  }
}

// ================= layer 2 fused GAT + classifier + log_softmax =================
__global__ __launch_bounds__(256) void k_gat2(
    const int* __restrict__ rowptr, const unsigned short* __restrict__ csr16,
    const unsigned* __restrict__ h2u, const float* __restrict__ as2,
    const float* __restrict__ ad2, const float* __restrict__ b2,
    const float* __restrict__ Wc, const float* __restrict__ bc,
    float* __restrict__ out) {
  __shared__ float2 sw[4][64];
  const int t = threadIdx.x;
  const int wv = t >> 6;
  const int n = blockIdx.x * 4 + wv;
  if (n >= NN) return;
  const int p = t & 63;
  const int half = p >> 5;
  const int q = p & 31;
  const int beg = rowptr[n], end = rowptr[n + 1];
  const int deg = end - beg;
  const float adn = ad2[n];

  float acc0 = 0.f, acc1 = 0.f;
  float inv;

  if (deg <= 64) {
    int s = 0; float e = -1e30f;
    if (p < deg) {
      s = csr16[beg + p];
      e = as2[s] + adn;
      e = fmaxf(e, 0.2f * e);
    }
    float m = e;
#pragma unroll
    for (int off = 1; off < 64; off <<= 1) m = fmaxf(m, __shfl_xor(m, off));
    float w = (p < deg) ? __expf(e - m) : 0.f;
    float d = w;
#pragma unroll
    for (int off = 1; off < 64; off <<= 1) d += __shfl_xor(d, off);
    sw[wv][p] = make_float2(__int_as_float(s), w);
    __builtin_amdgcn_wave_barrier();
    inv = 1.f / (d + 1e-16f);

    int niter = (deg + 1) >> 1;
    int i = 0;
    for (; i + 2 <= niter; i += 2) {
      float2 a0 = sw[wv][2 * i + half];
      float2 a1 = sw[wv][2 * i + 2 + half];
      unsigned v0 = h2u[(__float_as_int(a0.x) << 5) + q];
      unsigned v1 = h2u[(__float_as_int(a1.x) << 5) + q];
      acc0 += a0.y * __uint_as_float(v0 << 16); acc1 += a0.y * __uint_as_float(v0 & 0xFFFF0000u);
      acc0 += a1.y * __uint_as_float(v1 << 16); acc1 += a1.y * __uint_as_float(v1 & 0xFFFF0000u);
    }
    if (i < niter) {
      float2 a = sw[wv][2 * i + half];
      unsigned v = h2u[(__float_as_int(a.x) << 5) + q];
      acc0 += a.y * __uint_as_float(v << 16); acc1 += a.y * __uint_as_float(v & 0xFFFF0000u);
    }
  } else {
    float m = -1e30f, d = 0.f;
    for (int k = beg + p; k < end; k += 64) {
      float e = as2[csr16[k]] + adn;
      e = fmaxf(e, 0.2f * e);
      if (e > m) { d *= __expf(m - e); m = e; }
      d += __expf(e - m);
    }
#pragma unroll
    for (int off = 1; off < 64; off <<= 1) {
      float mo = __shfl_xor(m, off), dd = __shfl_xor(d, off);
      float mn = fmaxf(m, mo);
      d = d * __expf(m - mn) + dd * __expf(mo - mn);
      m = mn;
    }
    inv = 1.f / (d + 1e-16f);
    for (int c0 = beg; c0 < end; c0 += 64) {
      int nc = end - c0; if (nc > 64) nc = 64;
      int s = 0; float w = 0.f;
      if (p < nc) {
        s = csr16[c0 + p];
        float e = as2[s] + adn;
        e = fmaxf(e, 0.2f * e);
        w = __expf(e - m);
      }
      __builtin_amdgcn_wave_barrier();
      sw[wv][p] = make_float2(__int_as_float(s), w);
      __builtin_amdgcn_wave_barrier();
      int niter = (nc + 1) >> 1;
      for (int i = 0; i < niter; ++i) {
        int j = 2 * i + half;
        float2 a = sw[wv][j < nc ? j : 0];
        float wj = (j < nc) ? a.y : 0.f;
        unsigned v = h2u[(__float_as_int(a.x) << 5) + q];
        acc0 += wj * __uint_as_float(v << 16); acc1 += wj * __uint_as_float(v & 0xFFFF0000u);
      }
      __builtin_amdgcn_wave_barrier();
    }
  }

  acc0 += __shfl_xor(acc0, 32);
  acc1 += __shfl_xor(acc1, 32);
  float v0 = acc0 * inv + b2[2 * q];
  float v1 = acc1 * inv + b2[2 * q + 1];
  v0 = v0 > 0.f ? v0 : expm1f(v0);
  v1 = v1 > 0.f ? v1 : expm1f(v1);
  float l0 = v0 * Wc[4 * q] + v1 * Wc[4 * q + 2];
  float l1 = v0 * Wc[4 * q + 1] + v1 * Wc[4 * q + 3];
#pragma unroll
  for (int off = 1; off < 32; off <<= 1) {
    l0 += __shfl_xor(l0, off);
    l1 += __shfl_xor(l1, off);
  }
  if (p == 0) {
    l0 += bc[0]; l1 += bc[1];
    float mx = fmaxf(l0, l1);
    float lse = mx + logf(expf(l0 - mx) + expf(l1 - mx));
    out[n * 2] = l0 - lse;
    out[n * 2 + 1] = l1 - lse;
  }
}

extern "C" void kernel_launch(void* const* d_in, const int* in_sizes, int n_in,
                              void* d_out, int out_size, void* d_ws, size_t ws_size,
                              hipStream_t stream) {
  const float* x    = (const float*)d_in[0];
  const int*   ei   = (const int*)d_in[1];
  const float* W1   = (const float*)d_in[2];
  const float* as1w = (const float*)d_in[3];
  const float* ad1w = (const float*)d_in[4];
  const float* b1   = (const float*)d_in[5];
  const float* W2   = (const float*)d_in[6];
  const float* as2w = (const float*)d_in[7];
  const float* ad2w = (const float*)d_in[8];
  const float* b2   = (const float*)d_in[9];
  const float* Wc   = (const float*)d_in[10];
  const float* bc   = (const float*)d_in[11];
  float* out = (float*)d_out;

  const int* src = ei;
  const int* dst = ei + NE;

  // ---- workspace layout ----
  char* p = (char*)d_ws;
  unsigned short* h1b = (unsigned short*)p; p += sizeof(unsigned short) * (long long)NN * 128;
  unsigned* out1b = (unsigned*)p; p += sizeof(unsigned) * (long long)NN * 32;
  unsigned short* h2b = (unsigned short*)p; p += sizeof(unsigned short) * (long long)NN * 64;
  float* as1  = (float*)p; p += sizeof(float) * NN * 2;
  float* ad1  = (float*)p; p += sizeof(float) * NN * 2;
  float* as2  = (float*)p; p += sizeof(float) * NN;
  float* ad2  = (float*)p; p += sizeof(float) * NN;
  int* deg     = (int*)p; p += sizeof(int) * NN;
  int* cursor  = (int*)p; p += sizeof(int) * NN;
  int* rowptr  = (int*)p; p += sizeof(int) * (NN + 1);
  int* part    = (int*)p; p += sizeof(int) * ((NSCAN + 63) & ~63);
  int* bcur    = (int*)p; p += sizeof(int) * ((NBUCK + 63) & ~63);
  unsigned* staging = (unsigned*)p; p += sizeof(unsigned) * (long long)NT;
  unsigned short* csr16 = (unsigned short*)p; p += sizeof(unsigned short) * (long long)NT;
  unsigned short* w1f = (unsigned short*)p; p += sizeof(unsigned short) * 128 * 128;
  unsigned short* w2f = (unsigned short*)p; p += sizeof(unsigned short) * 64 * 64;

  // ---- weight frags + CSR build ----
  k_prep<<<(128 * 128 + 64 * 64 + 255) / 256, 256, 0, stream>>>(W1, W2, w1f, w2f);
  k_csr_zero<<<(NN + 255) / 256, 256, 0, stream>>>(deg);
  k_csr_count<<<(NE / 4 + 255) / 256, 256, 0, stream>>>(dst, deg);
  k_scan1<<<NSCAN, SCAN_BLK, 0, stream>>>(deg, rowptr, part);
  k_scan2<<<1, 64, 0, stream>>>(part);
  k_scan3<<<NSCAN, SCAN_BLK, 0, stream>>>(rowptr, cursor, part);
  k_binit<<<1, 256, 0, stream>>>(rowptr, bcur);
  k_bucket<<<NBLK_B, 256, 0, stream>>>(src, dst, bcur, staging);
  k_scatter2<<<NBUCK, 256, 0, stream>>>(staging, rowptr, cursor, csr16);

  // ---- layer 1 ----
  k_gemm1<<<(NN + 63) / 64, 256, 0, stream>>>(x, w1f, as1w, ad1w, h1b, as1, ad1);
  k_gat1<<<(NN + 3) / 4, 256, 0, stream>>>(rowptr, csr16, (const unsigned*)h1b,
                                           (const float2*)as1, (const float2*)ad1, b1, out1b);

  // ---- layer 2 ----
  k_gemm2<<<(NN + 63) / 64, 256, 0, stream>>>((const unsigned short*)out1b, w2f,
                                              as2w, ad2w, h2b, as2, ad2);
  k_gat2<<<(NN + 3) / 4, 256, 0, stream>>>(rowptr, csr16, (const unsigned*)h2b,
                                           as2, ad2, b2, Wc, bc, out);
}